// Round 8
// baseline (451.594 us; speedup 1.0000x reference)
//
#include <hip/hip_runtime.h>
#include <cstdint>
#include <cstddef>

// Problem constants (match reference)
#define NNODES 20000
#define NEDGES 640000
#define IN_F   128
#define CL1_F  256
#define CL2_F  128
#define OUT_F  10
#define BN_EPS 1e-5f

#define NC     256                // edge chunks for cnt/fill (2500 edges each)
#define CE     (NEDGES / NC)
#define HALFN  10000              // node half-range for LDS histograms

typedef unsigned short u16;

// ---------------- bf16 helpers ----------------

__device__ __forceinline__ float bf2f(u16 u) {
    union { uint32_t i; float f; } v; v.i = ((uint32_t)u) << 16; return v.f;
}
__device__ __forceinline__ u16 f2bf(float f) {
    union { float f; uint32_t i; } v; v.f = f;
    uint32_t r = v.i + 0x7fffu + ((v.i >> 16) & 1u);   // RNE
    return (u16)(r >> 16);
}
__device__ __forceinline__ void bf2x2(uint32_t u, float& lo, float& hi) {
    union { uint32_t i; float f; } a, b;
    a.i = u << 16; b.i = u & 0xffff0000u;
    lo = a.f; hi = b.f;
}
__device__ __forceinline__ uint32_t f2bf2(float lo, float hi) {
    return (uint32_t)f2bf(lo) | ((uint32_t)f2bf(hi) << 16);
}

// ---------------- CSC build: LDS histograms (cnt + fixed-point deg fused) ----------------

// Per-chunk: dst counts (u16 packed) + src-degree sums (u16 fixed point, w*1024).
// Max per-(chunk,node) degree sum ~8*1024 << 65536, no overflow/carry.
__launch_bounds__(256)
__global__ void cntdeg_hist(const int* __restrict__ ei, const float* __restrict__ ew,
                            u16* __restrict__ cnt_h, u16* __restrict__ degq_h, int E, int N) {
    __shared__ uint32_t scnt[HALFN / 2];   // 20 KB
    __shared__ uint32_t sdeg[HALFN / 2];   // 20 KB
    int chunk = blockIdx.x;
    int e0 = chunk * CE, e1 = e0 + CE;
    for (int half = 0; half < 2; ++half) {
        int lo = half * HALFN;
        for (int i = threadIdx.x; i < HALFN / 2; i += 256) { scnt[i] = 0; sdeg[i] = 0; }
        __syncthreads();
        for (int e = e0 + threadIdx.x; e < e1; e += 256) {
            int r = ei[e];
            int c = ei[E + e];
            int ci = c - lo;
            if ((unsigned)ci < HALFN) atomicAdd(&scnt[ci >> 1], 1u << ((ci & 1) * 16));
            int ri = r - lo;
            if ((unsigned)ri < HALFN) {
                float w = (r == c) ? 0.0f : ew[e];
                uint32_t q = (uint32_t)(w * 1024.0f + 0.5f);
                atomicAdd(&sdeg[ri >> 1], q << ((ri & 1) * 16));
            }
        }
        __syncthreads();
        for (int i = threadIdx.x; i < HALFN; i += 256) {
            cnt_h[(size_t)chunk * N + lo + i]  = (u16)((scnt[i >> 1] >> ((i & 1) * 16)) & 0xffffu);
            degq_h[(size_t)chunk * N + lo + i] = (u16)((sdeg[i >> 1] >> ((i & 1) * 16)) & 0xffffu);
        }
        __syncthreads();
    }
}

__global__ void reduce_dis(const u16* __restrict__ cnt_h, const u16* __restrict__ degq_h,
                           int* __restrict__ tot, float* __restrict__ dis, int N) {
    int i = blockIdx.x * blockDim.x + threadIdx.x;
    if (i >= N) return;
    int t = 0;
    uint32_t dq = 0;
#pragma unroll 8
    for (int c = 0; c < NC; ++c) {
        t  += cnt_h[(size_t)c * N + i];
        dq += degq_h[(size_t)c * N + i];
    }
    tot[i] = t;
    float d = (float)dq * (1.0f / 1024.0f);
    dis[i] = (d > 0.0f) ? rsqrtf(d) : 0.0f;
}

__global__ void scan_kernel(const int* __restrict__ tot, int* __restrict__ rowptr, int N) {
    __shared__ int sums[256];
    int t = threadIdx.x;
    int per = (N + 255) / 256;
    int s0 = t * per, s1 = min(s0 + per, N);
    int s = 0;
    for (int i = s0; i < s1; ++i) s += tot[i];
    sums[t] = s;
    __syncthreads();
    if (t == 0) {
        int run = 0;
        for (int i = 0; i < 256; ++i) { int v = sums[i]; sums[i] = run; run += v; }
        rowptr[N] = run;
    }
    __syncthreads();
    int run = sums[t];
    for (int i = s0; i < s1; ++i) { rowptr[i] = run; run += tot[i]; }
}

__global__ void mkbase(const int* __restrict__ rowptr, const u16* __restrict__ cnt_h,
                       int* __restrict__ baseT, int N) {
    int i = blockIdx.x * blockDim.x + threadIdx.x;
    if (i >= N) return;
    int run = rowptr[i];
#pragma unroll 8
    for (int c = 0; c < NC; ++c) {
        baseT[(size_t)c * N + i] = run;
        run += cnt_h[(size_t)c * N + i];
    }
}

// fill CSC: packed 4-byte records (src u16 | bf16 weight << 16)
__launch_bounds__(256)
__global__ void fill_kernel(const int* __restrict__ ei, const float* __restrict__ ew,
                            const float* __restrict__ dis, const int* __restrict__ baseT,
                            uint32_t* __restrict__ erec, int E, int N) {
    __shared__ uint32_t srank[NNODES / 2];  // 40 KB
    int chunk = blockIdx.x;
    int e0 = chunk * CE, e1 = e0 + CE;
    for (int i = threadIdx.x; i < NNODES / 2; i += 256) srank[i] = 0;
    __syncthreads();
    for (int e = e0 + threadIdx.x; e < e1; e += 256) {
        int r = ei[e];
        int c = ei[E + e];
        float w = (r == c) ? 0.0f : ew[e];
        float wn = -(dis[r] * w * dis[c]);   // * (2/lambda_max) = *1
        int sh = (c & 1) * 16;
        uint32_t old = atomicAdd(&srank[c >> 1], 1u << sh);
        int rank = (old >> sh) & 0xffff;
        int pos = baseT[(size_t)chunk * N + c] + rank;
        erec[pos] = (uint32_t)r | ((uint32_t)f2bf(wn) << 16);
    }
}

// ---------------- conversions (weights + x in one kernel) ----------------
// W1 (4,128,256) -> W1t[256][512];  W2 (4,256,128) -> W2t[512][256];  x -> A1 slice0 (ld 512)
__global__ void conv_all(const float* __restrict__ W1, u16* __restrict__ W1t,
                         const float* __restrict__ W2, u16* __restrict__ W2t,
                         const float* __restrict__ x, u16* __restrict__ A1) {
    int i = blockIdx.x * blockDim.x + threadIdx.x;
    const int S1 = 512 * 256;
    const int S2 = 4 * 256 * 128;
    const int SX = NNODES * 128;
    if (i < S1) {
        int k = i / 256, n = i - k * 256;
        W1t[(size_t)n * 512 + k] = f2bf(W1[i]);
    } else if (i < S1 + S2) {
        int j = i - S1;
        int kc = j / (256 * 128);
        int rem = j - kc * 256 * 128;
        int ci = rem / 128, co = rem - ci * 128;
        W2t[(size_t)(kc * 128 + co) * 256 + ci] = f2bf(W2[j]);
    } else if (i < S1 + S2 + SX) {
        int j = i - S1 - S2;
        int n = j >> 7, f = j & 127;
        A1[(size_t)n * 512 + f] = f2bf(x[j]);
    }
}

// ---------------- general spmm (CSC gather, F=128, 32 threads/node, unroll-8) ----------------
// tout[n] = s * sum_p w[p]*tin[src[p]] + c1*t1[n] + c2*t2[n]  (+bias, relu if flag)
__launch_bounds__(256)
__global__ void spmm_cl(const int* __restrict__ rowptr, const uint32_t* __restrict__ erec,
                        const u16* __restrict__ tin, int ldi,
                        const u16* __restrict__ t1, int ld1, float c1,
                        const u16* __restrict__ t2, int ld2, float c2,
                        u16* __restrict__ tout, int ldo,
                        const float* __restrict__ bias, int doReluBias,
                        int N, float s) {
    int gid = blockIdx.x * blockDim.x + threadIdx.x;
    int n = gid >> 5;
    if (n >= N) return;
    int f = (gid & 31) << 2;                 // 4 features per thread
    int p = rowptr[n], pe = rowptr[n + 1];
    float a0 = 0.f, a1 = 0.f, a2 = 0.f, a3 = 0.f;
    for (; p + 7 < pe; p += 8) {
        uint32_t rr[8];
        uint2 vv[8];
#pragma unroll
        for (int u = 0; u < 8; ++u) rr[u] = erec[p + u];
#pragma unroll
        for (int u = 0; u < 8; ++u)
            vv[u] = *(const uint2*)(tin + (size_t)(rr[u] & 0xffffu) * ldi + f);
#pragma unroll
        for (int u = 0; u < 8; ++u) {
            float w = bf2f((u16)(rr[u] >> 16));
            float f0, f1, f2, f3;
            bf2x2(vv[u].x, f0, f1); bf2x2(vv[u].y, f2, f3);
            a0 += w * f0; a1 += w * f1; a2 += w * f2; a3 += w * f3;
        }
    }
    for (; p < pe; ++p) {
        uint32_t r0 = erec[p];
        uint2 v0 = *(const uint2*)(tin + (size_t)(r0 & 0xffffu) * ldi + f);
        float w = bf2f((u16)(r0 >> 16));
        float f0, f1, f2, f3;
        bf2x2(v0.x, f0, f1); bf2x2(v0.y, f2, f3);
        a0 += w * f0; a1 += w * f1; a2 += w * f2; a3 += w * f3;
    }
    a0 *= s; a1 *= s; a2 *= s; a3 *= s;
    if (t1) {
        uint2 v = *(const uint2*)(t1 + (size_t)n * ld1 + f);
        float f0, f1, f2, f3;
        bf2x2(v.x, f0, f1); bf2x2(v.y, f2, f3);
        a0 += c1 * f0; a1 += c1 * f1; a2 += c1 * f2; a3 += c1 * f3;
    }
    if (t2) {
        uint2 v = *(const uint2*)(t2 + (size_t)n * ld2 + f);
        float f0, f1, f2, f3;
        bf2x2(v.x, f0, f1); bf2x2(v.y, f2, f3);
        a0 += c2 * f0; a1 += c2 * f1; a2 += c2 * f2; a3 += c2 * f3;
    }
    if (doReluBias) {
        a0 = fmaxf(a0 + bias[f + 0], 0.0f);
        a1 = fmaxf(a1 + bias[f + 1], 0.0f);
        a2 = fmaxf(a2 + bias[f + 2], 0.0f);
        a3 = fmaxf(a3 + bias[f + 3], 0.0f);
    }
    uint2 o;
    o.x = f2bf2(a0, a1);
    o.y = f2bf2(a2, a3);
    *(uint2*)(tout + (size_t)n * ldo + f) = o;
}

// ---------------- bf16 MFMA GEMM, 128x128 tile ----------------
// C = A[M,K] @ Bt[N,K]^T (+bias) (relu opt); out fp32 or bf16. N % 128 == 0, K % 64 == 0.

typedef __attribute__((ext_vector_type(8))) short short8;
typedef __attribute__((ext_vector_type(4))) float floatx4;

#define GBM 128
#define GBN 128
#define GBK 64

__launch_bounds__(256)
__global__ void gemm_mfma(const u16* __restrict__ A, const u16* __restrict__ Bt,
                          const float* __restrict__ bias, void* __restrict__ Cout,
                          int M, int N, int K, int doRelu, int outBf) {
    __shared__ __align__(16) u16 As[GBM][GBK + 8];   // stride 144 B (9x16B): 2-way LDS aliasing only
    __shared__ __align__(16) u16 Bs[GBN][GBK + 8];

    int tid = threadIdx.x;
    int lane = tid & 63;
    int wave = tid >> 6;
    int wm = (wave & 1) * 64;
    int wn = (wave >> 1) * 64;
    int rowBase = blockIdx.x * GBM;
    int colBase = blockIdx.y * GBN;

    floatx4 acc[4][4];
#pragma unroll
    for (int i = 0; i < 4; ++i)
#pragma unroll
        for (int j = 0; j < 4; ++j) {
            acc[i][j][0] = 0.f; acc[i][j][1] = 0.f; acc[i][j][2] = 0.f; acc[i][j][3] = 0.f;
        }

    int sr = tid >> 3;             // 0..31
    int sc = (tid & 7) * 8;        // 0..56

    for (int k0 = 0; k0 < K; k0 += GBK) {
#pragma unroll
        for (int h = 0; h < 4; ++h) {
            int r = sr + h * 32;
            int gm = rowBase + r;
            uint4 v = make_uint4(0, 0, 0, 0);
            if (gm < M) v = *(const uint4*)(A + (size_t)gm * K + k0 + sc);
            *(uint4*)&As[r][sc] = v;
            int gn = colBase + r;                    // N multiple of 128 -> no guard
            uint4 w = *(const uint4*)(Bt + (size_t)gn * K + k0 + sc);
            *(uint4*)&Bs[r][sc] = w;
        }
        __syncthreads();

        int mrow = lane & 15;
        int kq = (lane >> 4) * 8;
#pragma unroll
        for (int kk = 0; kk < GBK; kk += 32) {
            short8 af[4], bfr[4];
#pragma unroll
            for (int i = 0; i < 4; ++i) af[i] = *(const short8*)&As[wm + i * 16 + mrow][kk + kq];
#pragma unroll
            for (int j = 0; j < 4; ++j) bfr[j] = *(const short8*)&Bs[wn + j * 16 + mrow][kk + kq];
#pragma unroll
            for (int i = 0; i < 4; ++i)
#pragma unroll
                for (int j = 0; j < 4; ++j)
                    acc[i][j] = __builtin_amdgcn_mfma_f32_16x16x32_bf16(af[i], bfr[j], acc[i][j], 0, 0, 0);
        }
        __syncthreads();
    }

    int cn0 = colBase + wn + (lane & 15);
    int rq = (lane >> 4) * 4;
    float* Cf = (float*)Cout;
    u16*   Cb = (u16*)Cout;
#pragma unroll
    for (int i = 0; i < 4; ++i) {
#pragma unroll
        for (int r = 0; r < 4; ++r) {
            int m = rowBase + wm + i * 16 + rq + r;
            if (m >= M) continue;
#pragma unroll
            for (int j = 0; j < 4; ++j) {
                int n = cn0 + j * 16;
                float v = acc[i][j][r];
                if (bias) v += bias[n];
                if (doRelu) v = fmaxf(v, 0.0f);
                if (outBf) Cb[(size_t)m * N + n] = f2bf(v);
                else       Cf[(size_t)m * N + n] = v;
            }
        }
    }
}

// ---------------- batchnorm stats (applies folded into GEMM/linear) ----------------

#define BN_ROWS 64
__global__ void bn_stats_bf(const u16* __restrict__ h, int N, int C,
                            float* __restrict__ sums, float* __restrict__ sumsq) {
    int c = threadIdx.x;
    int r0 = blockIdx.x * BN_ROWS;
    int r1 = min(r0 + BN_ROWS, N);
    float s = 0.f, q = 0.f;
    for (int r = r0; r < r1; ++r) {
        float v = bf2f(h[(size_t)r * C + c]);
        s += v;
        q += v * v;
    }
    atomicAdd(&sums[c], s);
    atomicAdd(&sumsq[c], q);
}

// fold BN1 into W2t (in place); bn_final computed inline per block.
// block n (0..511), 256 threads (one per channel k).
__launch_bounds__(256)
__global__ void fold_w2(u16* __restrict__ W2t, const float* __restrict__ sums,
                        const float* __restrict__ sumsq, const float* __restrict__ gamma,
                        const float* __restrict__ beta, float* __restrict__ rowvec, float invN) {
    __shared__ float red[4];
    int n = blockIdx.x;
    int k = threadIdx.x;
    float m = sums[k] * invN;
    float var = sumsq[k] * invN - m * m;
    float sc = gamma[k] / sqrtf(var + BN_EPS);
    float sh = beta[k] - m * sc;
    float wf = bf2f(W2t[(size_t)n * 256 + k]);
    W2t[(size_t)n * 256 + k] = f2bf(wf * sc);
    float part = sh * wf;
#pragma unroll
    for (int off = 32; off > 0; off >>= 1) part += __shfl_down(part, off);
    if ((k & 63) == 0) red[k >> 6] = part;
    __syncthreads();
    if (k == 0) rowvec[n] = red[0] + red[1] + red[2] + red[3];
}

// fold BN2 into Wlin; bn_final inline. block o (0..9), 128 threads.
__launch_bounds__(128)
__global__ void fold_lin(const float* __restrict__ Wlin, const float* __restrict__ blin,
                         const float* __restrict__ sums, const float* __restrict__ sumsq,
                         const float* __restrict__ gamma, const float* __restrict__ beta,
                         float* __restrict__ Wlp, float* __restrict__ blin_p, float invN) {
    __shared__ float red[2];
    int o = blockIdx.x;
    int c = threadIdx.x;
    float m = sums[c] * invN;
    float var = sumsq[c] * invN - m * m;
    float sc = gamma[c] / sqrtf(var + BN_EPS);
    float sh = beta[c] - m * sc;
    float wf = Wlin[(size_t)o * 128 + c];
    Wlp[(size_t)o * 128 + c] = wf * sc;
    float part = sh * wf;
#pragma unroll
    for (int off = 32; off > 0; off >>= 1) part += __shfl_down(part, off);
    if ((c & 63) == 0) red[c >> 6] = part;
    __syncthreads();
    if (c == 0) blin_p[o] = blin[o] + red[0] + red[1];
}

// ---------------- final linear (bf16 input, BN folded) ----------------

__global__ void final_linear_bf(const u16* __restrict__ g, const float* __restrict__ Wlp,
                                const float* __restrict__ blin_p, float* __restrict__ out, int N) {
    __shared__ float Ws[OUT_F * CL2_F];
    __shared__ float bs[OUT_F];
    for (int i = threadIdx.x; i < OUT_F * CL2_F; i += 256) Ws[i] = Wlp[i];
    if (threadIdx.x < OUT_F) bs[threadIdx.x] = blin_p[threadIdx.x];
    __syncthreads();
    int idx = blockIdx.x * 256 + threadIdx.x;
    if (idx >= N * OUT_F) return;
    int n = idx / OUT_F, o = idx - n * OUT_F;
    const u16* gr = g + (size_t)n * CL2_F;
    const float* wr = Ws + o * CL2_F;
    float acc = 0.f;
#pragma unroll 8
    for (int f = 0; f < CL2_F; ++f) acc += bf2f(gr[f]) * wr[f];
    out[idx] = acc + bs[o];
}

// ---------------- host launch ----------------

extern "C" void kernel_launch(void* const* d_in, const int* in_sizes, int n_in,
                              void* d_out, int out_size, void* d_ws, size_t ws_size,
                              hipStream_t stream) {
    const float* x      = (const float*)d_in[0];
    const int*   ei     = (const int*)d_in[1];
    const float* ew     = (const float*)d_in[2];
    const float* W1     = (const float*)d_in[3];
    const float* b1     = (const float*)d_in[4];
    const float* W2     = (const float*)d_in[5];
    const float* b2     = (const float*)d_in[6];
    const float* gamma1 = (const float*)d_in[7];
    const float* beta1  = (const float*)d_in[8];
    const float* gamma2 = (const float*)d_in[9];
    const float* beta2  = (const float*)d_in[10];
    const float* Wlin   = (const float*)d_in[11];
    const float* blin   = (const float*)d_in[12];
    float* out = (float*)d_out;

    const int N = NNODES, E = NEDGES;

    // workspace (~90.4 MB, no aliasing except Hc=A1)
    char* base = (char*)d_ws;
    u16*     cnt_h  = (u16*)    (base + 0);           // NC*N u16 = 10.24 MB
    u16*     degq_h = (u16*)    (base + 10240000);    // NC*N u16 = 10.24 MB
    int*     baseT  = (int*)    (base + 20480000);    // NC*N i32 = 20.48 MB
    u16*     A1     = (u16*)    (base + 40960000);    // N*512 bf16 = 20.48 MB
    u16*     Hc     = A1;                             // aliased (A1 dead after GEMM1)
    u16*     h1bf   = (u16*)    (base + 61440000);    // N*256 bf16 = 10.24 MB
    u16*     pbuf   = (u16*)    (base + 71680000);    // N*128 bf16 = 5.12 MB
    u16*     bb2    = (u16*)    (base + 76800000);    // N*128 bf16
    u16*     bb1    = (u16*)    (base + 81920000);    // N*128 bf16
    uint32_t* erec  = (uint32_t*)(base + 87040000);   // E*4 = 2.56 MB
    u16*     W1t    = (u16*)    (base + 89600000);    // 256*512 bf16
    u16*     W2t    = (u16*)    (base + 89862144);    // 512*256 bf16
    float*   Wlp    = (float*)  (base + 90124288);    // 10*128 f32
    float*   rowvec = (float*)  (base + 90129408);    // 512 f32
    float*   blin_p = (float*)  (base + 90131456);    // 10 f32 (pad)
    int*     rowptr = (int*)    (base + 90131520);    // N+1
    int*     tot    = (int*)    (base + 90211536);    // N
    float*   dis    = (float*)  (base + 90291536);    // N
    float*   bns    = (float*)  (base + 90371536);    // 256
    float*   bnq     = bns + 256;

    dim3 blk(256);

    // --- conversions + CSC build (zero global atomics, full-chip grids) ---
    conv_all<<<dim3((512 * 256 + 4 * 256 * 128 + N * 128 + 255) / 256), blk, 0, stream>>>(
        W1, W1t, W2, W2t, x, A1);
    cntdeg_hist<<<dim3(NC), blk, 0, stream>>>(ei, ew, cnt_h, degq_h, E, N);
    reduce_dis<<<dim3((N + 255) / 256), blk, 0, stream>>>(cnt_h, degq_h, tot, dis, N);
    scan_kernel<<<dim3(1), blk, 0, stream>>>(tot, rowptr, N);
    mkbase<<<dim3((N + 255) / 256), blk, 0, stream>>>(rowptr, cnt_h, baseT, N);
    fill_kernel<<<dim3(NC), blk, 0, stream>>>(ei, ew, dis, baseT, erec, E, N);

    dim3 gS(((N << 5) + 255) / 256);   // spmm grid: 32 threads/node

    // --- layer 1: A1 = [x|T1|T2|T3] bf16, ld 512 ---
    spmm_cl<<<gS, blk, 0, stream>>>(rowptr, erec, A1 + 0,   512, nullptr,  512, 0.f,
                                    nullptr, 512, 0.f, A1 + 128, 512, nullptr, 0, N, 1.0f);
    spmm_cl<<<gS, blk, 0, stream>>>(rowptr, erec, A1 + 128, 512, A1 + 0,   512, -1.f,
                                    nullptr, 512, 0.f, A1 + 256, 512, nullptr, 0, N, 2.0f);
    spmm_cl<<<gS, blk, 0, stream>>>(rowptr, erec, A1 + 256, 512, A1 + 128, 512, -1.f,
                                    nullptr, 512, 0.f, A1 + 384, 512, nullptr, 0, N, 2.0f);

    // --- GEMM1: h1bf = relu(A1 @ W1 + b1) bf16  [M=20000, N=256, K=512] ---
    gemm_mfma<<<dim3((N + GBM - 1) / GBM, CL1_F / GBN), blk, 0, stream>>>(
        A1, W1t, b1, h1bf, N, CL1_F, 512, 1, 1);

    // --- BN1 stats -> fold into W2t + rowvec ---
    hipMemsetAsync(bns, 0, 2 * 256 * sizeof(float), stream);
    bn_stats_bf<<<dim3((N + BN_ROWS - 1) / BN_ROWS), dim3(CL1_F), 0, stream>>>(h1bf, N, CL1_F, bns, bnq);
    fold_w2<<<dim3(512), dim3(256), 0, stream>>>(W2t, bns, bnq, gamma1, beta1, rowvec, 1.0f / N);

    // --- GEMM2: Hc = h1bf @ W2t' + rowvec  [M=20000, N=512, K=256] bf16 out ---
    gemm_mfma<<<dim3((N + GBM - 1) / GBM, 512 / GBN), blk, 0, stream>>>(
        h1bf, W2t, rowvec, Hc, N, 512, 256, 0, 1);

    // --- layer 2 via Clenshaw (F=128 spmms) ---
    spmm_cl<<<gS, blk, 0, stream>>>(rowptr, erec, Hc + 384, 512, Hc + 256, 512, 1.f,
                                    nullptr, 512, 0.f, bb2, 128, nullptr, 0, N, 2.0f);
    spmm_cl<<<gS, blk, 0, stream>>>(rowptr, erec, bb2, 128, Hc + 384, 512, -1.f,
                                    Hc + 128, 512, 1.f, bb1, 128, nullptr, 0, N, 2.0f);
    spmm_cl<<<gS, blk, 0, stream>>>(rowptr, erec, bb1, 128, bb2, 128, -1.f,
                                    Hc + 0, 512, 1.f, pbuf, 128, b2, 1, N, 1.0f);

    // --- BN2 stats -> fold into Wlin ---
    hipMemsetAsync(bns, 0, 2 * 256 * sizeof(float), stream);
    bn_stats_bf<<<dim3((N + BN_ROWS - 1) / BN_ROWS), dim3(CL2_F), 0, stream>>>(pbuf, N, CL2_F, bns, bnq);
    fold_lin<<<dim3(OUT_F), dim3(CL2_F), 0, stream>>>(Wlin, blin, bns, bnq, gamma2, beta2, Wlp, blin_p, 1.0f / N);

    // --- final linear (bf16 input, folded BN) ---
    final_linear_bf<<<dim3((N * OUT_F + 255) / 256), blk, 0, stream>>>(pbuf, Wlp, blin_p, out, N);
}

// Round 9
// 418.900 us; speedup vs baseline: 1.0780x; 1.0780x over previous
//
#include <hip/hip_runtime.h>
#include <cstdint>
#include <cstddef>

// Problem constants (match reference)
#define NNODES 20000
#define NEDGES 640000
#define IN_F   128
#define CL1_F  256
#define CL2_F  128
#define OUT_F  10
#define BN_EPS 1e-5f

#define NC     256                // edge chunks for cnt/fill (2500 edges each)
#define CE     (NEDGES / NC)
#define HALFN  10000              // node half-range for LDS histograms

typedef unsigned short u16;

// ---------------- bf16 helpers ----------------

__device__ __forceinline__ float bf2f(u16 u) {
    union { uint32_t i; float f; } v; v.i = ((uint32_t)u) << 16; return v.f;
}
__device__ __forceinline__ u16 f2bf(float f) {
    union { float f; uint32_t i; } v; v.f = f;
    uint32_t r = v.i + 0x7fffu + ((v.i >> 16) & 1u);   // RNE
    return (u16)(r >> 16);
}
__device__ __forceinline__ void bf2x2(uint32_t u, float& lo, float& hi) {
    union { uint32_t i; float f; } a, b;
    a.i = u << 16; b.i = u & 0xffff0000u;
    lo = a.f; hi = b.f;
}
__device__ __forceinline__ uint32_t f2bf2(float lo, float hi) {
    return (uint32_t)f2bf(lo) | ((uint32_t)f2bf(hi) << 16);
}
__device__ __forceinline__ void unpack8(uint4 v, float* o) {
    bf2x2(v.x, o[0], o[1]); bf2x2(v.y, o[2], o[3]);
    bf2x2(v.z, o[4], o[5]); bf2x2(v.w, o[6], o[7]);
}

// ---------------- CSC build: LDS histograms (cnt + fixed-point deg fused) ----------------

__launch_bounds__(256)
__global__ void cntdeg_hist(const int* __restrict__ ei, const float* __restrict__ ew,
                            u16* __restrict__ cnt_h, u16* __restrict__ degq_h, int E, int N) {
    __shared__ uint32_t scnt[HALFN / 2];   // 20 KB
    __shared__ uint32_t sdeg[HALFN / 2];   // 20 KB
    int chunk = blockIdx.x;
    int e0 = chunk * CE, e1 = e0 + CE;
    for (int half = 0; half < 2; ++half) {
        int lo = half * HALFN;
        for (int i = threadIdx.x; i < HALFN / 2; i += 256) { scnt[i] = 0; sdeg[i] = 0; }
        __syncthreads();
        for (int e = e0 + threadIdx.x; e < e1; e += 256) {
            int r = ei[e];
            int c = ei[E + e];
            int ci = c - lo;
            if ((unsigned)ci < HALFN) atomicAdd(&scnt[ci >> 1], 1u << ((ci & 1) * 16));
            int ri = r - lo;
            if ((unsigned)ri < HALFN) {
                float w = (r == c) ? 0.0f : ew[e];
                uint32_t q = (uint32_t)(w * 1024.0f + 0.5f);
                atomicAdd(&sdeg[ri >> 1], q << ((ri & 1) * 16));
            }
        }
        __syncthreads();
        for (int i = threadIdx.x; i < HALFN; i += 256) {
            cnt_h[(size_t)chunk * N + lo + i]  = (u16)((scnt[i >> 1] >> ((i & 1) * 16)) & 0xffffu);
            degq_h[(size_t)chunk * N + lo + i] = (u16)((sdeg[i >> 1] >> ((i & 1) * 16)) & 0xffffu);
        }
        __syncthreads();
    }
}

__global__ void reduce_dis(const u16* __restrict__ cnt_h, const u16* __restrict__ degq_h,
                           int* __restrict__ tot, float* __restrict__ dis, int N) {
    int i = blockIdx.x * blockDim.x + threadIdx.x;
    if (i >= N) return;
    int t = 0;
    uint32_t dq = 0;
#pragma unroll 8
    for (int c = 0; c < NC; ++c) {
        t  += cnt_h[(size_t)c * N + i];
        dq += degq_h[(size_t)c * N + i];
    }
    tot[i] = t;
    float d = (float)dq * (1.0f / 1024.0f);
    dis[i] = (d > 0.0f) ? rsqrtf(d) : 0.0f;
}

__global__ void scan_kernel(const int* __restrict__ tot, int* __restrict__ rowptr, int N) {
    __shared__ int sums[256];
    int t = threadIdx.x;
    int per = (N + 255) / 256;
    int s0 = t * per, s1 = min(s0 + per, N);
    int s = 0;
    for (int i = s0; i < s1; ++i) s += tot[i];
    sums[t] = s;
    __syncthreads();
    if (t == 0) {
        int run = 0;
        for (int i = 0; i < 256; ++i) { int v = sums[i]; sums[i] = run; run += v; }
        rowptr[N] = run;
    }
    __syncthreads();
    int run = sums[t];
    for (int i = s0; i < s1; ++i) { rowptr[i] = run; run += tot[i]; }
}

__global__ void mkbase(const int* __restrict__ rowptr, const u16* __restrict__ cnt_h,
                       int* __restrict__ baseT, int N) {
    int i = blockIdx.x * blockDim.x + threadIdx.x;
    if (i >= N) return;
    int run = rowptr[i];
#pragma unroll 8
    for (int c = 0; c < NC; ++c) {
        baseT[(size_t)c * N + i] = run;
        run += cnt_h[(size_t)c * N + i];
    }
}

// fill CSC: packed 4-byte records (src u16 | bf16 weight << 16)
__launch_bounds__(256)
__global__ void fill_kernel(const int* __restrict__ ei, const float* __restrict__ ew,
                            const float* __restrict__ dis, const int* __restrict__ baseT,
                            uint32_t* __restrict__ erec, int E, int N) {
    __shared__ uint32_t srank[NNODES / 2];  // 40 KB
    int chunk = blockIdx.x;
    int e0 = chunk * CE, e1 = e0 + CE;
    for (int i = threadIdx.x; i < NNODES / 2; i += 256) srank[i] = 0;
    __syncthreads();
    for (int e = e0 + threadIdx.x; e < e1; e += 256) {
        int r = ei[e];
        int c = ei[E + e];
        float w = (r == c) ? 0.0f : ew[e];
        float wn = -(dis[r] * w * dis[c]);   // * (2/lambda_max) = *1
        int sh = (c & 1) * 16;
        uint32_t old = atomicAdd(&srank[c >> 1], 1u << sh);
        int rank = (old >> sh) & 0xffff;
        int pos = baseT[(size_t)chunk * N + c] + rank;
        erec[pos] = (uint32_t)r | ((uint32_t)f2bf(wn) << 16);
    }
}

// ---------------- conversions (weights + x in one kernel) ----------------
// W1 (4,128,256) -> W1t[256][512];  W2 (4,256,128) -> W2t[512][256];  x -> A1 slice0 (ld 512)
__global__ void conv_all(const float* __restrict__ W1, u16* __restrict__ W1t,
                         const float* __restrict__ W2, u16* __restrict__ W2t,
                         const float* __restrict__ x, u16* __restrict__ A1) {
    int i = blockIdx.x * blockDim.x + threadIdx.x;
    const int S1 = 512 * 256;
    const int S2 = 4 * 256 * 128;
    const int SX = NNODES * 128;
    if (i < S1) {
        int k = i / 256, n = i - k * 256;
        W1t[(size_t)n * 512 + k] = f2bf(W1[i]);
    } else if (i < S1 + S2) {
        int j = i - S1;
        int kc = j / (256 * 128);
        int rem = j - kc * 256 * 128;
        int ci = rem / 128, co = rem - ci * 128;
        W2t[(size_t)(kc * 128 + co) * 256 + ci] = f2bf(W2[j]);
    } else if (i < S1 + S2 + SX) {
        int j = i - S1 - S2;
        int n = j >> 7, f = j & 127;
        A1[(size_t)n * 512 + f] = f2bf(x[j]);
    }
}

// ---------------- general spmm (CSC gather, F=128, 16 threads/node, uint4, unroll-4) ----------------
// tout[n] = s * sum_p w[p]*tin[src[p]] + c1*t1[n] + c2*t2[n]  (+bias, relu if flag)
__launch_bounds__(256)
__global__ void spmm_cl(const int* __restrict__ rowptr, const uint32_t* __restrict__ erec,
                        const u16* __restrict__ tin, int ldi,
                        const u16* __restrict__ t1, int ld1, float c1,
                        const u16* __restrict__ t2, int ld2, float c2,
                        u16* __restrict__ tout, int ldo,
                        const float* __restrict__ bias, int doReluBias,
                        int N, float s) {
    int gid = blockIdx.x * blockDim.x + threadIdx.x;
    int n = gid >> 4;
    if (n >= N) return;
    int f = (gid & 15) << 3;
    int p = rowptr[n], pe = rowptr[n + 1];
    float acc[8] = {};
    // unroll-4: 4 record loads (contiguous), then 4 independent row loads
    for (; p + 3 < pe; p += 4) {
        uint32_t r0 = erec[p], r1 = erec[p + 1], r2 = erec[p + 2], r3 = erec[p + 3];
        uint4 v0 = *(const uint4*)(tin + (size_t)(r0 & 0xffffu) * ldi + f);
        uint4 v1 = *(const uint4*)(tin + (size_t)(r1 & 0xffffu) * ldi + f);
        uint4 v2 = *(const uint4*)(tin + (size_t)(r2 & 0xffffu) * ldi + f);
        uint4 v3 = *(const uint4*)(tin + (size_t)(r3 & 0xffffu) * ldi + f);
        float w0 = bf2f((u16)(r0 >> 16)), w1 = bf2f((u16)(r1 >> 16));
        float w2 = bf2f((u16)(r2 >> 16)), w3 = bf2f((u16)(r3 >> 16));
        float fa[8];
        unpack8(v0, fa);
#pragma unroll
        for (int q = 0; q < 8; ++q) acc[q] += w0 * fa[q];
        unpack8(v1, fa);
#pragma unroll
        for (int q = 0; q < 8; ++q) acc[q] += w1 * fa[q];
        unpack8(v2, fa);
#pragma unroll
        for (int q = 0; q < 8; ++q) acc[q] += w2 * fa[q];
        unpack8(v3, fa);
#pragma unroll
        for (int q = 0; q < 8; ++q) acc[q] += w3 * fa[q];
    }
    for (; p < pe; ++p) {
        uint32_t r0 = erec[p];
        uint4 v0 = *(const uint4*)(tin + (size_t)(r0 & 0xffffu) * ldi + f);
        float w0 = bf2f((u16)(r0 >> 16));
        float fa[8];
        unpack8(v0, fa);
#pragma unroll
        for (int q = 0; q < 8; ++q) acc[q] += w0 * fa[q];
    }
#pragma unroll
    for (int q = 0; q < 8; ++q) acc[q] *= s;
    if (t1) {
        uint4 v = *(const uint4*)(t1 + (size_t)n * ld1 + f);
        float fv[8]; unpack8(v, fv);
#pragma unroll
        for (int q = 0; q < 8; ++q) acc[q] += c1 * fv[q];
    }
    if (t2) {
        uint4 v = *(const uint4*)(t2 + (size_t)n * ld2 + f);
        float fv[8]; unpack8(v, fv);
#pragma unroll
        for (int q = 0; q < 8; ++q) acc[q] += c2 * fv[q];
    }
    if (doReluBias) {
#pragma unroll
        for (int q = 0; q < 8; ++q) acc[q] = fmaxf(acc[q] + bias[f + q], 0.0f);
    }
    uint4 o;
    o.x = f2bf2(acc[0], acc[1]);
    o.y = f2bf2(acc[2], acc[3]);
    o.z = f2bf2(acc[4], acc[5]);
    o.w = f2bf2(acc[6], acc[7]);
    *(uint4*)(tout + (size_t)n * ldo + f) = o;
}

// ---------------- bf16 MFMA GEMM, 128x128 tile ----------------
// C = A[M,K] @ Bt[N,K]^T (+bias) (relu opt); out fp32 or bf16. N % 128 == 0, K % 64 == 0.

typedef __attribute__((ext_vector_type(8))) short short8;
typedef __attribute__((ext_vector_type(4))) float floatx4;

#define GBM 128
#define GBN 128
#define GBK 64

__launch_bounds__(256)
__global__ void gemm_mfma(const u16* __restrict__ A, const u16* __restrict__ Bt,
                          const float* __restrict__ bias, void* __restrict__ Cout,
                          int M, int N, int K, int doRelu, int outBf) {
    __shared__ __align__(16) u16 As[GBM][GBK + 8];   // stride 144 B: 2-way LDS aliasing only
    __shared__ __align__(16) u16 Bs[GBN][GBK + 8];

    int tid = threadIdx.x;
    int lane = tid & 63;
    int wave = tid >> 6;
    int wm = (wave & 1) * 64;
    int wn = (wave >> 1) * 64;
    int rowBase = blockIdx.x * GBM;
    int colBase = blockIdx.y * GBN;

    floatx4 acc[4][4];
#pragma unroll
    for (int i = 0; i < 4; ++i)
#pragma unroll
        for (int j = 0; j < 4; ++j) {
            acc[i][j][0] = 0.f; acc[i][j][1] = 0.f; acc[i][j][2] = 0.f; acc[i][j][3] = 0.f;
        }

    int sr = tid >> 3;             // 0..31
    int sc = (tid & 7) * 8;        // 0..56

    for (int k0 = 0; k0 < K; k0 += GBK) {
#pragma unroll
        for (int h = 0; h < 4; ++h) {
            int r = sr + h * 32;
            int gm = rowBase + r;
            uint4 v = make_uint4(0, 0, 0, 0);
            if (gm < M) v = *(const uint4*)(A + (size_t)gm * K + k0 + sc);
            *(uint4*)&As[r][sc] = v;
            int gn = colBase + r;                    // N multiple of 128 -> no guard
            uint4 w = *(const uint4*)(Bt + (size_t)gn * K + k0 + sc);
            *(uint4*)&Bs[r][sc] = w;
        }
        __syncthreads();

        int mrow = lane & 15;
        int kq = (lane >> 4) * 8;
#pragma unroll
        for (int kk = 0; kk < GBK; kk += 32) {
            short8 af[4], bfr[4];
#pragma unroll
            for (int i = 0; i < 4; ++i) af[i] = *(const short8*)&As[wm + i * 16 + mrow][kk + kq];
#pragma unroll
            for (int j = 0; j < 4; ++j) bfr[j] = *(const short8*)&Bs[wn + j * 16 + mrow][kk + kq];
#pragma unroll
            for (int i = 0; i < 4; ++i)
#pragma unroll
                for (int j = 0; j < 4; ++j)
                    acc[i][j] = __builtin_amdgcn_mfma_f32_16x16x32_bf16(af[i], bfr[j], acc[i][j], 0, 0, 0);
        }
        __syncthreads();
    }

    int cn0 = colBase + wn + (lane & 15);
    int rq = (lane >> 4) * 4;
    float* Cf = (float*)Cout;
    u16*   Cb = (u16*)Cout;
#pragma unroll
    for (int i = 0; i < 4; ++i) {
#pragma unroll
        for (int r = 0; r < 4; ++r) {
            int m = rowBase + wm + i * 16 + rq + r;
            if (m >= M) continue;
#pragma unroll
            for (int j = 0; j < 4; ++j) {
                int n = cn0 + j * 16;
                float v = acc[i][j][r];
                if (bias) v += bias[n];
                if (doRelu) v = fmaxf(v, 0.0f);
                if (outBf) Cb[(size_t)m * N + n] = f2bf(v);
                else       Cf[(size_t)m * N + n] = v;
            }
        }
    }
}

// ---------------- batchnorm stats (applies folded into GEMM/linear) ----------------

#define BN_ROWS 64
__global__ void bn_stats_bf(const u16* __restrict__ h, int N, int C,
                            float* __restrict__ sums, float* __restrict__ sumsq) {
    int c = threadIdx.x;
    int r0 = blockIdx.x * BN_ROWS;
    int r1 = min(r0 + BN_ROWS, N);
    float s = 0.f, q = 0.f;
    for (int r = r0; r < r1; ++r) {
        float v = bf2f(h[(size_t)r * C + c]);
        s += v;
        q += v * v;
    }
    atomicAdd(&sums[c], s);
    atomicAdd(&sumsq[c], q);
}

// fold BN1 into W2t (in place); bn_final computed inline per block.
__launch_bounds__(256)
__global__ void fold_w2(u16* __restrict__ W2t, const float* __restrict__ sums,
                        const float* __restrict__ sumsq, const float* __restrict__ gamma,
                        const float* __restrict__ beta, float* __restrict__ rowvec, float invN) {
    __shared__ float red[4];
    int n = blockIdx.x;
    int k = threadIdx.x;
    float m = sums[k] * invN;
    float var = sumsq[k] * invN - m * m;
    float sc = gamma[k] / sqrtf(var + BN_EPS);
    float sh = beta[k] - m * sc;
    float wf = bf2f(W2t[(size_t)n * 256 + k]);
    W2t[(size_t)n * 256 + k] = f2bf(wf * sc);
    float part = sh * wf;
#pragma unroll
    for (int off = 32; off > 0; off >>= 1) part += __shfl_down(part, off);
    if ((k & 63) == 0) red[k >> 6] = part;
    __syncthreads();
    if (k == 0) rowvec[n] = red[0] + red[1] + red[2] + red[3];
}

// fold BN2 into Wlin; bn_final inline.
__launch_bounds__(128)
__global__ void fold_lin(const float* __restrict__ Wlin, const float* __restrict__ blin,
                         const float* __restrict__ sums, const float* __restrict__ sumsq,
                         const float* __restrict__ gamma, const float* __restrict__ beta,
                         float* __restrict__ Wlp, float* __restrict__ blin_p, float invN) {
    __shared__ float red[2];
    int o = blockIdx.x;
    int c = threadIdx.x;
    float m = sums[c] * invN;
    float var = sumsq[c] * invN - m * m;
    float sc = gamma[c] / sqrtf(var + BN_EPS);
    float sh = beta[c] - m * sc;
    float wf = Wlin[(size_t)o * 128 + c];
    Wlp[(size_t)o * 128 + c] = wf * sc;
    float part = sh * wf;
#pragma unroll
    for (int off = 32; off > 0; off >>= 1) part += __shfl_down(part, off);
    if ((c & 63) == 0) red[c >> 6] = part;
    __syncthreads();
    if (c == 0) blin_p[o] = blin[o] + red[0] + red[1];
}

// ---------------- final linear (bf16 input, BN folded) ----------------

__global__ void final_linear_bf(const u16* __restrict__ g, const float* __restrict__ Wlp,
                                const float* __restrict__ blin_p, float* __restrict__ out, int N) {
    __shared__ float Ws[OUT_F * CL2_F];
    __shared__ float bs[OUT_F];
    for (int i = threadIdx.x; i < OUT_F * CL2_F; i += 256) Ws[i] = Wlp[i];
    if (threadIdx.x < OUT_F) bs[threadIdx.x] = blin_p[threadIdx.x];
    __syncthreads();
    int idx = blockIdx.x * 256 + threadIdx.x;
    if (idx >= N * OUT_F) return;
    int n = idx / OUT_F, o = idx - n * OUT_F;
    const u16* gr = g + (size_t)n * CL2_F;
    const float* wr = Ws + o * CL2_F;
    float acc = 0.f;
#pragma unroll 8
    for (int f = 0; f < CL2_F; ++f) acc += bf2f(gr[f]) * wr[f];
    out[idx] = acc + bs[o];
}

// ---------------- host launch ----------------

extern "C" void kernel_launch(void* const* d_in, const int* in_sizes, int n_in,
                              void* d_out, int out_size, void* d_ws, size_t ws_size,
                              hipStream_t stream) {
    const float* x      = (const float*)d_in[0];
    const int*   ei     = (const int*)d_in[1];
    const float* ew     = (const float*)d_in[2];
    const float* W1     = (const float*)d_in[3];
    const float* b1     = (const float*)d_in[4];
    const float* W2     = (const float*)d_in[5];
    const float* b2     = (const float*)d_in[6];
    const float* gamma1 = (const float*)d_in[7];
    const float* beta1  = (const float*)d_in[8];
    const float* gamma2 = (const float*)d_in[9];
    const float* beta2  = (const float*)d_in[10];
    const float* Wlin   = (const float*)d_in[11];
    const float* blin   = (const float*)d_in[12];
    float* out = (float*)d_out;

    const int N = NNODES, E = NEDGES;

    // workspace (~90.4 MB, no aliasing except Hc=A1)
    char* base = (char*)d_ws;
    u16*     cnt_h  = (u16*)    (base + 0);           // NC*N u16 = 10.24 MB
    u16*     degq_h = (u16*)    (base + 10240000);    // NC*N u16 = 10.24 MB
    int*     baseT  = (int*)    (base + 20480000);    // NC*N i32 = 20.48 MB
    u16*     A1     = (u16*)    (base + 40960000);    // N*512 bf16 = 20.48 MB
    u16*     Hc     = A1;                             // aliased (A1 dead after GEMM1)
    u16*     h1bf   = (u16*)    (base + 61440000);    // N*256 bf16 = 10.24 MB
    u16*     pbuf   = (u16*)    (base + 71680000);    // N*128 bf16 = 5.12 MB
    u16*     bb2    = (u16*)    (base + 76800000);    // N*128 bf16
    u16*     bb1    = (u16*)    (base + 81920000);    // N*128 bf16
    uint32_t* erec  = (uint32_t*)(base + 87040000);   // E*4 = 2.56 MB
    u16*     W1t    = (u16*)    (base + 89600000);    // 256*512 bf16
    u16*     W2t    = (u16*)    (base + 89862144);    // 512*256 bf16
    float*   Wlp    = (float*)  (base + 90124288);    // 10*128 f32
    float*   rowvec = (float*)  (base + 90129408);    // 512 f32
    float*   blin_p = (float*)  (base + 90131456);    // 10 f32 (pad)
    int*     rowptr = (int*)    (base + 90131520);    // N+1
    int*     tot    = (int*)    (base + 90211536);    // N
    float*   dis    = (float*)  (base + 90291536);    // N
    float*   bns    = (float*)  (base + 90371536);    // 256
    float*   bnq     = bns + 256;

    dim3 blk(256);

    // --- conversions + CSC build (zero global atomics, full-chip grids) ---
    conv_all<<<dim3((512 * 256 + 4 * 256 * 128 + N * 128 + 255) / 256), blk, 0, stream>>>(
        W1, W1t, W2, W2t, x, A1);
    cntdeg_hist<<<dim3(NC), blk, 0, stream>>>(ei, ew, cnt_h, degq_h, E, N);
    reduce_dis<<<dim3((N + 255) / 256), blk, 0, stream>>>(cnt_h, degq_h, tot, dis, N);
    scan_kernel<<<dim3(1), blk, 0, stream>>>(tot, rowptr, N);
    mkbase<<<dim3((N + 255) / 256), blk, 0, stream>>>(rowptr, cnt_h, baseT, N);
    fill_kernel<<<dim3(NC), blk, 0, stream>>>(ei, ew, dis, baseT, erec, E, N);

    dim3 gS(((N << 4) + 255) / 256);   // spmm grid: 16 threads/node

    // --- layer 1: A1 = [x|T1|T2|T3] bf16, ld 512 ---
    spmm_cl<<<gS, blk, 0, stream>>>(rowptr, erec, A1 + 0,   512, nullptr,  512, 0.f,
                                    nullptr, 512, 0.f, A1 + 128, 512, nullptr, 0, N, 1.0f);
    spmm_cl<<<gS, blk, 0, stream>>>(rowptr, erec, A1 + 128, 512, A1 + 0,   512, -1.f,
                                    nullptr, 512, 0.f, A1 + 256, 512, nullptr, 0, N, 2.0f);
    spmm_cl<<<gS, blk, 0, stream>>>(rowptr, erec, A1 + 256, 512, A1 + 128, 512, -1.f,
                                    nullptr, 512, 0.f, A1 + 384, 512, nullptr, 0, N, 2.0f);

    // --- GEMM1: h1bf = relu(A1 @ W1 + b1) bf16  [M=20000, N=256, K=512] ---
    gemm_mfma<<<dim3((N + GBM - 1) / GBM, CL1_F / GBN), blk, 0, stream>>>(
        A1, W1t, b1, h1bf, N, CL1_F, 512, 1, 1);

    // --- BN1 stats -> fold into W2t + rowvec ---
    hipMemsetAsync(bns, 0, 2 * 256 * sizeof(float), stream);
    bn_stats_bf<<<dim3((N + BN_ROWS - 1) / BN_ROWS), dim3(CL1_F), 0, stream>>>(h1bf, N, CL1_F, bns, bnq);
    fold_w2<<<dim3(512), dim3(256), 0, stream>>>(W2t, bns, bnq, gamma1, beta1, rowvec, 1.0f / N);

    // --- GEMM2: Hc = h1bf @ W2t' + rowvec  [M=20000, N=512, K=256] bf16 out ---
    gemm_mfma<<<dim3((N + GBM - 1) / GBM, 512 / GBN), blk, 0, stream>>>(
        h1bf, W2t, rowvec, Hc, N, 512, 256, 0, 1);

    // --- layer 2 via Clenshaw (F=128 spmms) ---
    spmm_cl<<<gS, blk, 0, stream>>>(rowptr, erec, Hc + 384, 512, Hc + 256, 512, 1.f,
                                    nullptr, 512, 0.f, bb2, 128, nullptr, 0, N, 2.0f);
    spmm_cl<<<gS, blk, 0, stream>>>(rowptr, erec, bb2, 128, Hc + 384, 512, -1.f,
                                    Hc + 128, 512, 1.f, bb1, 128, nullptr, 0, N, 2.0f);
    spmm_cl<<<gS, blk, 0, stream>>>(rowptr, erec, bb1, 128, bb2, 128, -1.f,
                                    Hc + 0, 512, 1.f, pbuf, 128, b2, 1, N, 1.0f);

    // --- BN2 stats -> fold into Wlin ---
    hipMemsetAsync(bns, 0, 2 * 256 * sizeof(float), stream);
    bn_stats_bf<<<dim3((N + BN_ROWS - 1) / BN_ROWS), dim3(CL2_F), 0, stream>>>(pbuf, N, CL2_F, bns, bnq);
    fold_lin<<<dim3(OUT_F), dim3(CL2_F), 0, stream>>>(Wlin, blin, bns, bnq, gamma2, beta2, Wlp, blin_p, 1.0f / N);

    // --- final linear (bf16 input, folded BN) ---
    final_linear_bf<<<dim3((N * OUT_F + 255) / 256), blk, 0, stream>>>(pbuf, Wlp, blin_p, out, N);
}

// Round 11
// 391.566 us; speedup vs baseline: 1.1533x; 1.0698x over previous
//
#include <hip/hip_runtime.h>
#include <cstdint>
#include <cstddef>

// Problem constants (match reference)
#define NNODES 20000
#define NEDGES 640000
#define IN_F   128
#define CL1_F  256
#define CL2_F  128
#define OUT_F  10
#define BN_EPS 1e-5f

#define NC     256                // edge chunks for cnt/fill (2500 edges each)
#define CE     (NEDGES / NC)
#define HALFN  10000              // node half-range for LDS histograms

// conv workload appended to the hist launch
#define CONVN  (512 * 256 + 4 * 256 * 128 + NNODES * 128)

typedef unsigned short u16;

// ---------------- bf16 helpers ----------------

__device__ __forceinline__ float bf2f(u16 u) {
    union { uint32_t i; float f; } v; v.i = ((uint32_t)u) << 16; return v.f;
}
__device__ __forceinline__ u16 f2bf(float f) {
    union { float f; uint32_t i; } v; v.f = f;
    uint32_t r = v.i + 0x7fffu + ((v.i >> 16) & 1u);   // RNE
    return (u16)(r >> 16);
}
__device__ __forceinline__ void bf2x2(uint32_t u, float& lo, float& hi) {
    union { uint32_t i; float f; } a, b;
    a.i = u << 16; b.i = u & 0xffff0000u;
    lo = a.f; hi = b.f;
}
__device__ __forceinline__ uint32_t f2bf2(float lo, float hi) {
    return (uint32_t)f2bf(lo) | ((uint32_t)f2bf(hi) << 16);
}
__device__ __forceinline__ void unpack8(uint4 v, float* o) {
    bf2x2(v.x, o[0], o[1]); bf2x2(v.y, o[2], o[3]);
    bf2x2(v.z, o[4], o[5]); bf2x2(v.w, o[6], o[7]);
}

// ---------------- fused: CSC hist (blocks 0..NC) + weight/x conversion (rest) ----------------

__launch_bounds__(256)
__global__ void build_hist_conv(const int* __restrict__ ei, const float* __restrict__ ew,
                                u16* __restrict__ cnt_h, u16* __restrict__ degq_h,
                                const float* __restrict__ W1, u16* __restrict__ W1t,
                                const float* __restrict__ W2, u16* __restrict__ W2t,
                                const float* __restrict__ x, u16* __restrict__ A1,
                                int E, int N) {
    __shared__ uint32_t scnt[HALFN / 2];   // 20 KB
    __shared__ uint32_t sdeg[HALFN / 2];   // 20 KB
    int b = blockIdx.x;
    if (b < NC) {
        // ---- per-chunk histogram: dst counts + fixed-point src-degree sums ----
        int e0 = b * CE, e1 = e0 + CE;
        for (int half = 0; half < 2; ++half) {
            int lo = half * HALFN;
            for (int i = threadIdx.x; i < HALFN / 2; i += 256) { scnt[i] = 0; sdeg[i] = 0; }
            __syncthreads();
            for (int e = e0 + threadIdx.x; e < e1; e += 256) {
                int r = ei[e];
                int c = ei[E + e];
                int ci = c - lo;
                if ((unsigned)ci < HALFN) atomicAdd(&scnt[ci >> 1], 1u << ((ci & 1) * 16));
                int ri = r - lo;
                if ((unsigned)ri < HALFN) {
                    float w = (r == c) ? 0.0f : ew[e];
                    uint32_t q = (uint32_t)(w * 1024.0f + 0.5f);
                    atomicAdd(&sdeg[ri >> 1], q << ((ri & 1) * 16));
                }
            }
            __syncthreads();
            for (int i = threadIdx.x; i < HALFN; i += 256) {
                cnt_h[(size_t)b * N + lo + i]  = (u16)((scnt[i >> 1] >> ((i & 1) * 16)) & 0xffffu);
                degq_h[(size_t)b * N + lo + i] = (u16)((sdeg[i >> 1] >> ((i & 1) * 16)) & 0xffffu);
            }
            __syncthreads();
        }
    } else {
        // ---- conversions: W1->W1t, W2->W2t, x->A1 slice0 ----
        int i = (b - NC) * 256 + threadIdx.x;
        const int S1 = 512 * 256;
        const int S2 = 4 * 256 * 128;
        const int SX = NNODES * 128;
        if (i < S1) {
            int k = i / 256, n = i - k * 256;
            W1t[(size_t)n * 512 + k] = f2bf(W1[i]);
        } else if (i < S1 + S2) {
            int j = i - S1;
            int kc = j / (256 * 128);
            int rem = j - kc * 256 * 128;
            int ci = rem / 128, co = rem - ci * 128;
            W2t[(size_t)(kc * 128 + co) * 256 + ci] = f2bf(W2[j]);
        } else if (i < S1 + S2 + SX) {
            int j = i - S1 - S2;
            int n = j >> 7, f = j & 127;
            A1[(size_t)n * 512 + f] = f2bf(x[j]);
        }
    }
}

__global__ void reduce_dis(const u16* __restrict__ cnt_h, const u16* __restrict__ degq_h,
                           int* __restrict__ tot, float* __restrict__ dis, int N) {
    int i = blockIdx.x * blockDim.x + threadIdx.x;
    if (i >= N) return;
    int t = 0;
    uint32_t dq = 0;
#pragma unroll 8
    for (int c = 0; c < NC; ++c) {
        t  += cnt_h[(size_t)c * N + i];
        dq += degq_h[(size_t)c * N + i];
    }
    tot[i] = t;
    float d = (float)dq * (1.0f / 1024.0f);
    dis[i] = (d > 0.0f) ? rsqrtf(d) : 0.0f;
}

__global__ void scan_kernel(const int* __restrict__ tot, int* __restrict__ rowptr, int N) {
    __shared__ int sums[256];
    int t = threadIdx.x;
    int per = (N + 255) / 256;
    int s0 = t * per, s1 = min(s0 + per, N);
    int s = 0;
    for (int i = s0; i < s1; ++i) s += tot[i];
    sums[t] = s;
    __syncthreads();
    if (t == 0) {
        int run = 0;
        for (int i = 0; i < 256; ++i) { int v = sums[i]; sums[i] = run; run += v; }
        rowptr[N] = run;
    }
    __syncthreads();
    int run = sums[t];
    for (int i = s0; i < s1; ++i) { rowptr[i] = run; run += tot[i]; }
}

// per-(chunk,node) fill base as u16 delta vs rowptr (delta <= node degree < 65536)
__global__ void mkbase(const u16* __restrict__ cnt_h, u16* __restrict__ baseD, int N) {
    int i = blockIdx.x * blockDim.x + threadIdx.x;
    if (i >= N) return;
    int run = 0;
#pragma unroll 8
    for (int c = 0; c < NC; ++c) {
        baseD[(size_t)c * N + i] = (u16)run;
        run += cnt_h[(size_t)c * N + i];
    }
}

// fill CSC: packed 4-byte records (src u16 | bf16 weight << 16)
__launch_bounds__(256)
__global__ void fill_kernel(const int* __restrict__ ei, const float* __restrict__ ew,
                            const float* __restrict__ dis, const int* __restrict__ rowptr,
                            const u16* __restrict__ baseD,
                            uint32_t* __restrict__ erec, int E, int N) {
    __shared__ uint32_t srank[NNODES / 2];  // 40 KB
    int chunk = blockIdx.x;
    int e0 = chunk * CE, e1 = e0 + CE;
    for (int i = threadIdx.x; i < NNODES / 2; i += 256) srank[i] = 0;
    __syncthreads();
    for (int e = e0 + threadIdx.x; e < e1; e += 256) {
        int r = ei[e];
        int c = ei[E + e];
        float w = (r == c) ? 0.0f : ew[e];
        float wn = -(dis[r] * w * dis[c]);   // * (2/lambda_max) = *1
        int sh = (c & 1) * 16;
        uint32_t old = atomicAdd(&srank[c >> 1], 1u << sh);
        int rank = (old >> sh) & 0xffff;
        int pos = rowptr[c] + (int)baseD[(size_t)chunk * N + c] + rank;
        erec[pos] = (uint32_t)r | ((uint32_t)f2bf(wn) << 16);
    }
}

// ---------------- general spmm (CSC gather, F=128, 16 threads/node, uint4, unroll-4) ----------------
// tout[n] = s * sum_p w[p]*tin[src[p]] + c1*t1[n] + c2*t2[n]  (+bias, relu if flag)
__launch_bounds__(256)
__global__ void spmm_cl(const int* __restrict__ rowptr, const uint32_t* __restrict__ erec,
                        const u16* __restrict__ tin, int ldi,
                        const u16* __restrict__ t1, int ld1, float c1,
                        const u16* __restrict__ t2, int ld2, float c2,
                        u16* __restrict__ tout, int ldo,
                        const float* __restrict__ bias, int doReluBias,
                        int N, float s) {
    int gid = blockIdx.x * blockDim.x + threadIdx.x;
    int n = gid >> 4;
    if (n >= N) return;
    int f = (gid & 15) << 3;
    int p = rowptr[n], pe = rowptr[n + 1];
    float acc[8] = {};
    for (; p + 3 < pe; p += 4) {
        uint32_t r0 = erec[p], r1 = erec[p + 1], r2 = erec[p + 2], r3 = erec[p + 3];
        uint4 v0 = *(const uint4*)(tin + (size_t)(r0 & 0xffffu) * ldi + f);
        uint4 v1 = *(const uint4*)(tin + (size_t)(r1 & 0xffffu) * ldi + f);
        uint4 v2 = *(const uint4*)(tin + (size_t)(r2 & 0xffffu) * ldi + f);
        uint4 v3 = *(const uint4*)(tin + (size_t)(r3 & 0xffffu) * ldi + f);
        float w0 = bf2f((u16)(r0 >> 16)), w1 = bf2f((u16)(r1 >> 16));
        float w2 = bf2f((u16)(r2 >> 16)), w3 = bf2f((u16)(r3 >> 16));
        float fa[8];
        unpack8(v0, fa);
#pragma unroll
        for (int q = 0; q < 8; ++q) acc[q] += w0 * fa[q];
        unpack8(v1, fa);
#pragma unroll
        for (int q = 0; q < 8; ++q) acc[q] += w1 * fa[q];
        unpack8(v2, fa);
#pragma unroll
        for (int q = 0; q < 8; ++q) acc[q] += w2 * fa[q];
        unpack8(v3, fa);
#pragma unroll
        for (int q = 0; q < 8; ++q) acc[q] += w3 * fa[q];
    }
    for (; p < pe; ++p) {
        uint32_t r0 = erec[p];
        uint4 v0 = *(const uint4*)(tin + (size_t)(r0 & 0xffffu) * ldi + f);
        float w0 = bf2f((u16)(r0 >> 16));
        float fa[8];
        unpack8(v0, fa);
#pragma unroll
        for (int q = 0; q < 8; ++q) acc[q] += w0 * fa[q];
    }
#pragma unroll
    for (int q = 0; q < 8; ++q) acc[q] *= s;
    if (t1) {
        uint4 v = *(const uint4*)(t1 + (size_t)n * ld1 + f);
        float fv[8]; unpack8(v, fv);
#pragma unroll
        for (int q = 0; q < 8; ++q) acc[q] += c1 * fv[q];
    }
    if (t2) {
        uint4 v = *(const uint4*)(t2 + (size_t)n * ld2 + f);
        float fv[8]; unpack8(v, fv);
#pragma unroll
        for (int q = 0; q < 8; ++q) acc[q] += c2 * fv[q];
    }
    if (doReluBias) {
#pragma unroll
        for (int q = 0; q < 8; ++q) acc[q] = fmaxf(acc[q] + bias[f + q], 0.0f);
    }
    uint4 o;
    o.x = f2bf2(acc[0], acc[1]);
    o.y = f2bf2(acc[2], acc[3]);
    o.z = f2bf2(acc[4], acc[5]);
    o.w = f2bf2(acc[6], acc[7]);
    *(uint4*)(tout + (size_t)n * ldo + f) = o;
}

// ---------------- bf16 MFMA GEMM, 128x128 tile (+optional fused BN column stats) ----------------

typedef __attribute__((ext_vector_type(8))) short short8;
typedef __attribute__((ext_vector_type(4))) float floatx4;

#define GBM 128
#define GBN 128
#define GBK 64

__launch_bounds__(256)
__global__ void gemm_mfma(const u16* __restrict__ A, const u16* __restrict__ Bt,
                          const float* __restrict__ bias, void* __restrict__ Cout,
                          float* __restrict__ ssum, float* __restrict__ ssq,
                          int M, int N, int K, int doRelu, int outBf) {
    __shared__ __align__(16) u16 As[GBM][GBK + 8];   // stride 144 B: 2-way LDS aliasing only
    __shared__ __align__(16) u16 Bs[GBN][GBK + 8];
    __shared__ float colsum[GBN], colsq[GBN];

    int tid = threadIdx.x;
    int lane = tid & 63;
    int wave = tid >> 6;
    int wm = (wave & 1) * 64;
    int wn = (wave >> 1) * 64;
    int rowBase = blockIdx.x * GBM;
    int colBase = blockIdx.y * GBN;

    floatx4 acc[4][4];
#pragma unroll
    for (int i = 0; i < 4; ++i)
#pragma unroll
        for (int j = 0; j < 4; ++j) {
            acc[i][j][0] = 0.f; acc[i][j][1] = 0.f; acc[i][j][2] = 0.f; acc[i][j][3] = 0.f;
        }

    int sr = tid >> 3;             // 0..31
    int sc = (tid & 7) * 8;        // 0..56

    for (int k0 = 0; k0 < K; k0 += GBK) {
#pragma unroll
        for (int h = 0; h < 4; ++h) {
            int r = sr + h * 32;
            int gm = rowBase + r;
            uint4 v = make_uint4(0, 0, 0, 0);
            if (gm < M) v = *(const uint4*)(A + (size_t)gm * K + k0 + sc);
            *(uint4*)&As[r][sc] = v;
            int gn = colBase + r;                    // N multiple of 128 -> no guard
            uint4 w = *(const uint4*)(Bt + (size_t)gn * K + k0 + sc);
            *(uint4*)&Bs[r][sc] = w;
        }
        __syncthreads();

        int mrow = lane & 15;
        int kq = (lane >> 4) * 8;
#pragma unroll
        for (int kk = 0; kk < GBK; kk += 32) {
            short8 af[4], bfr[4];
#pragma unroll
            for (int i = 0; i < 4; ++i) af[i] = *(const short8*)&As[wm + i * 16 + mrow][kk + kq];
#pragma unroll
            for (int j = 0; j < 4; ++j) bfr[j] = *(const short8*)&Bs[wn + j * 16 + mrow][kk + kq];
#pragma unroll
            for (int i = 0; i < 4; ++i)
#pragma unroll
                for (int j = 0; j < 4; ++j)
                    acc[i][j] = __builtin_amdgcn_mfma_f32_16x16x32_bf16(af[i], bfr[j], acc[i][j], 0, 0, 0);
        }
        __syncthreads();
    }

    if (ssum) {
        if (tid < GBN) { colsum[tid] = 0.f; colsq[tid] = 0.f; }
        __syncthreads();
    }

    int cn0 = colBase + wn + (lane & 15);
    int rq = (lane >> 4) * 4;
    float* Cf = (float*)Cout;
    u16*   Cb = (u16*)Cout;
#pragma unroll
    for (int j = 0; j < 4; ++j) {
        float ps = 0.f, pq = 0.f;
        int n = cn0 + j * 16;
#pragma unroll
        for (int i = 0; i < 4; ++i) {
#pragma unroll
            for (int r = 0; r < 4; ++r) {
                int m = rowBase + wm + i * 16 + rq + r;
                if (m >= M) continue;
                float v = acc[i][j][r];
                if (bias) v += bias[n];
                if (doRelu) v = fmaxf(v, 0.0f);
                if (outBf) {
                    u16 bb = f2bf(v);
                    Cb[(size_t)m * N + n] = bb;
                    if (ssum) { float vb = bf2f(bb); ps += vb; pq += vb * vb; }
                } else {
                    Cf[(size_t)m * N + n] = v;
                }
            }
        }
        if (ssum) {
            int lc = wn + j * 16 + (lane & 15);
            atomicAdd(&colsum[lc], ps);
            atomicAdd(&colsq[lc], pq);
        }
    }
    if (ssum) {
        __syncthreads();
        if (tid < GBN) {
            atomicAdd(&ssum[colBase + tid], colsum[tid]);
            atomicAdd(&ssq[colBase + tid], colsq[tid]);
        }
    }
}

// ---------------- batchnorm stats (BN2 only; BN1 fused into GEMM1) ----------------

#define BN_ROWS 64
__global__ void bn_stats_bf(const u16* __restrict__ h, int N, int C,
                            float* __restrict__ sums, float* __restrict__ sumsq) {
    int c = threadIdx.x;
    int r0 = blockIdx.x * BN_ROWS;
    int r1 = min(r0 + BN_ROWS, N);
    float s = 0.f, q = 0.f;
    for (int r = r0; r < r1; ++r) {
        float v = bf2f(h[(size_t)r * C + c]);
        s += v;
        q += v * v;
    }
    atomicAdd(&sums[c], s);
    atomicAdd(&sumsq[c], q);
}

// fold BN1 into W2t (in place); bn_final computed inline per block.
__launch_bounds__(256)
__global__ void fold_w2(u16* __restrict__ W2t, const float* __restrict__ sums,
                        const float* __restrict__ sumsq, const float* __restrict__ gamma,
                        const float* __restrict__ beta, float* __restrict__ rowvec, float invN) {
    __shared__ float red[4];
    int n = blockIdx.x;
    int k = threadIdx.x;
    float m = sums[k] * invN;
    float var = sumsq[k] * invN - m * m;
    float sc = gamma[k] / sqrtf(var + BN_EPS);
    float sh = beta[k] - m * sc;
    float wf = bf2f(W2t[(size_t)n * 256 + k]);
    W2t[(size_t)n * 256 + k] = f2bf(wf * sc);
    float part = sh * wf;
#pragma unroll
    for (int off = 32; off > 0; off >>= 1) part += __shfl_down(part, off);
    if ((k & 63) == 0) red[k >> 6] = part;
    __syncthreads();
    if (k == 0) rowvec[n] = red[0] + red[1] + red[2] + red[3];
}

// ---------------- final linear with inline BN2 fold (bf16 input) ----------------

__global__ void final_linear_bn(const u16* __restrict__ g, const float* __restrict__ Wlin,
                                const float* __restrict__ blin, const float* __restrict__ sums,
                                const float* __restrict__ sumsq, const float* __restrict__ gamma,
                                const float* __restrict__ beta, float* __restrict__ out,
                                int N, float invN) {
    __shared__ float Ws[OUT_F * CL2_F];
    __shared__ float bs[OUT_F];
    __shared__ float scs[CL2_F], shs[CL2_F];
    for (int i = threadIdx.x; i < OUT_F * CL2_F; i += 256) Ws[i] = Wlin[i];
    if (threadIdx.x < OUT_F) bs[threadIdx.x] = blin[threadIdx.x];
    if (threadIdx.x < CL2_F) {
        int c = threadIdx.x;
        float m = sums[c] * invN;
        float var = sumsq[c] * invN - m * m;
        float sc = gamma[c] / sqrtf(var + BN_EPS);
        scs[c] = sc;
        shs[c] = beta[c] - m * sc;
    }
    __syncthreads();
    int idx = blockIdx.x * 256 + threadIdx.x;
    if (idx >= N * OUT_F) return;
    int n = idx / OUT_F, o = idx - n * OUT_F;
    const u16* gr = g + (size_t)n * CL2_F;
    const float* wr = Ws + o * CL2_F;
    float acc = 0.f;
#pragma unroll 8
    for (int f = 0; f < CL2_F; ++f) acc += (bf2f(gr[f]) * scs[f] + shs[f]) * wr[f];
    out[idx] = acc + bs[o];
}

// ---------------- host launch ----------------

extern "C" void kernel_launch(void* const* d_in, const int* in_sizes, int n_in,
                              void* d_out, int out_size, void* d_ws, size_t ws_size,
                              hipStream_t stream) {
    const float* x      = (const float*)d_in[0];
    const int*   ei     = (const int*)d_in[1];
    const float* ew     = (const float*)d_in[2];
    const float* W1     = (const float*)d_in[3];
    const float* b1     = (const float*)d_in[4];
    const float* W2     = (const float*)d_in[5];
    const float* b2     = (const float*)d_in[6];
    const float* gamma1 = (const float*)d_in[7];
    const float* beta1  = (const float*)d_in[8];
    const float* gamma2 = (const float*)d_in[9];
    const float* beta2  = (const float*)d_in[10];
    const float* Wlin   = (const float*)d_in[11];
    const float* blin   = (const float*)d_in[12];
    float* out = (float*)d_out;

    const int N = NNODES, E = NEDGES;

    // workspace (~80.2 MB). NOTE R10 bug: baseD is NC*N u16 = 10.24 MB (NOT 5.12);
    // layout below gives it the full extent — no overlap with A1.
    char* base = (char*)d_ws;
    u16*     cnt_h  = (u16*)    (base + 0);           // NC*N u16 = 10.24 MB
    u16*     degq_h = (u16*)    (base + 10240000);    // NC*N u16 = 10.24 MB
    u16*     baseD  = (u16*)    (base + 20480000);    // NC*N u16 = 10.24 MB (ends 30,720,000)
    u16*     A1     = (u16*)    (base + 30720000);    // N*512 bf16 = 20.48 MB
    u16*     Hc     = A1;                             // aliased (A1 dead after GEMM1)
    u16*     h1bf   = (u16*)    (base + 51200000);    // N*256 bf16 = 10.24 MB
    u16*     pbuf   = (u16*)    (base + 61440000);    // N*128 bf16 = 5.12 MB
    u16*     bb2    = (u16*)    (base + 66560000);    // N*128 bf16
    u16*     bb1    = (u16*)    (base + 71680000);    // N*128 bf16
    uint32_t* erec  = (uint32_t*)(base + 76800000);   // E*4 = 2.56 MB
    u16*     W1t    = (u16*)    (base + 79360000);    // 256*512 bf16 = 262144
    u16*     W2t    = (u16*)    (base + 79622144);    // 512*256 bf16 = 262144
    float*   rowvec = (float*)  (base + 79884288);    // 512 f32
    int*     rowptr = (int*)    (base + 79886336);    // N+1
    int*     tot    = (int*)    (base + 79966352);    // N
    float*   dis    = (float*)  (base + 80046352);    // N
    float*   bns1   = (float*)  (base + 80126352);    // 256 (BN1 sums)
    float*   bnq1    = bns1 + 256;                    // 256 (BN1 sumsq)
    float*   bns2    = bnq1 + 256;                    // 256 (BN2 sums; 128 used)
    float*   bnq2    = bns2 + 256;                    // 256 (BN2 sumsq)

    dim3 blk(256);

    // --- zero all BN stat buffers once (GEMM1 accumulates into bns1/bnq1) ---
    hipMemsetAsync(bns1, 0, 4 * 256 * sizeof(float), stream);

    // --- fused: CSC histograms + all dtype conversions in one launch ---
    build_hist_conv<<<dim3(NC + (CONVN + 255) / 256), blk, 0, stream>>>(
        ei, ew, cnt_h, degq_h, W1, W1t, W2, W2t, x, A1, E, N);
    reduce_dis<<<dim3((N + 255) / 256), blk, 0, stream>>>(cnt_h, degq_h, tot, dis, N);
    scan_kernel<<<dim3(1), blk, 0, stream>>>(tot, rowptr, N);
    mkbase<<<dim3((N + 255) / 256), blk, 0, stream>>>(cnt_h, baseD, N);
    fill_kernel<<<dim3(NC), blk, 0, stream>>>(ei, ew, dis, rowptr, baseD, erec, E, N);

    dim3 gS(((N << 4) + 255) / 256);   // spmm grid: 16 threads/node

    // --- layer 1: A1 = [x|T1|T2|T3] bf16, ld 512 ---
    spmm_cl<<<gS, blk, 0, stream>>>(rowptr, erec, A1 + 0,   512, nullptr,  512, 0.f,
                                    nullptr, 512, 0.f, A1 + 128, 512, nullptr, 0, N, 1.0f);
    spmm_cl<<<gS, blk, 0, stream>>>(rowptr, erec, A1 + 128, 512, A1 + 0,   512, -1.f,
                                    nullptr, 512, 0.f, A1 + 256, 512, nullptr, 0, N, 2.0f);
    spmm_cl<<<gS, blk, 0, stream>>>(rowptr, erec, A1 + 256, 512, A1 + 128, 512, -1.f,
                                    nullptr, 512, 0.f, A1 + 384, 512, nullptr, 0, N, 2.0f);

    // --- GEMM1: h1bf = relu(A1 @ W1 + b1) bf16, fused BN1 column stats ---
    gemm_mfma<<<dim3((N + GBM - 1) / GBM, CL1_F / GBN), blk, 0, stream>>>(
        A1, W1t, b1, h1bf, bns1, bnq1, N, CL1_F, 512, 1, 1);

    // --- fold BN1 into W2t + rowvec ---
    fold_w2<<<dim3(512), dim3(256), 0, stream>>>(W2t, bns1, bnq1, gamma1, beta1, rowvec, 1.0f / N);

    // --- GEMM2: Hc = h1bf @ W2t' + rowvec  [M=20000, N=512, K=256] bf16 out ---
    gemm_mfma<<<dim3((N + GBM - 1) / GBM, 512 / GBN), blk, 0, stream>>>(
        h1bf, W2t, rowvec, Hc, nullptr, nullptr, N, 512, 256, 0, 1);

    // --- layer 2 via Clenshaw (F=128 spmms) ---
    spmm_cl<<<gS, blk, 0, stream>>>(rowptr, erec, Hc + 384, 512, Hc + 256, 512, 1.f,
                                    nullptr, 512, 0.f, bb2, 128, nullptr, 0, N, 2.0f);
    spmm_cl<<<gS, blk, 0, stream>>>(rowptr, erec, bb2, 128, Hc + 384, 512, -1.f,
                                    Hc + 128, 512, 1.f, bb1, 128, nullptr, 0, N, 2.0f);
    spmm_cl<<<gS, blk, 0, stream>>>(rowptr, erec, bb1, 128, bb2, 128, -1.f,
                                    Hc + 0, 512, 1.f, pbuf, 128, b2, 1, N, 1.0f);

    // --- BN2 stats ---
    bn_stats_bf<<<dim3((N + BN_ROWS - 1) / BN_ROWS), dim3(CL2_F), 0, stream>>>(pbuf, N, CL2_F, bns2, bnq2);

    // --- final linear with inline BN2 fold ---
    final_linear_bn<<<dim3((N * OUT_F + 255) / 256), blk, 0, stream>>>(
        pbuf, Wlin, blin, bns2, bnq2, gamma2, beta2, out, N, 1.0f / N);
}

// Round 12
// 382.930 us; speedup vs baseline: 1.1793x; 1.0226x over previous
//
#include <hip/hip_runtime.h>
#include <cstdint>
#include <cstddef>

// Problem constants (match reference)
#define NNODES 20000
#define NEDGES 640000
#define IN_F   128
#define CL1_F  256
#define CL2_F  128
#define OUT_F  10
#define BN_EPS 1e-5f

#define NC     256                // edge chunks for cnt/fill (2500 edges each)
#define CE     (NEDGES / NC)
#define HALFN  10000              // node half-range for LDS histograms

// conv workload appended to the hist launch
#define CONVN  (512 * 256 + 4 * 256 * 128 + NNODES * 128)

typedef unsigned short u16;

// ---------------- bf16 helpers ----------------

__device__ __forceinline__ float bf2f(u16 u) {
    union { uint32_t i; float f; } v; v.i = ((uint32_t)u) << 16; return v.f;
}
__device__ __forceinline__ u16 f2bf(float f) {
    union { float f; uint32_t i; } v; v.f = f;
    uint32_t r = v.i + 0x7fffu + ((v.i >> 16) & 1u);   // RNE
    return (u16)(r >> 16);
}
__device__ __forceinline__ void bf2x2(uint32_t u, float& lo, float& hi) {
    union { uint32_t i; float f; } a, b;
    a.i = u << 16; b.i = u & 0xffff0000u;
    lo = a.f; hi = b.f;
}
__device__ __forceinline__ uint32_t f2bf2(float lo, float hi) {
    return (uint32_t)f2bf(lo) | ((uint32_t)f2bf(hi) << 16);
}
__device__ __forceinline__ void unpack8(uint4 v, float* o) {
    bf2x2(v.x, o[0], o[1]); bf2x2(v.y, o[2], o[3]);
    bf2x2(v.z, o[4], o[5]); bf2x2(v.w, o[6], o[7]);
}

// ---------------- fused: CSC hist (blocks 0..NC) + weight/x conversion (rest) ----------------

__launch_bounds__(256)
__global__ void build_hist_conv(const int* __restrict__ ei, const float* __restrict__ ew,
                                u16* __restrict__ cnt_h, u16* __restrict__ degq_h,
                                const float* __restrict__ W1, u16* __restrict__ W1t,
                                const float* __restrict__ W2, u16* __restrict__ W2t,
                                const float* __restrict__ x, u16* __restrict__ A1,
                                int E, int N) {
    __shared__ uint32_t scnt[HALFN / 2];   // 20 KB
    __shared__ uint32_t sdeg[HALFN / 2];   // 20 KB
    int b = blockIdx.x;
    if (b < NC) {
        // ---- per-chunk histogram: dst counts + fixed-point src-degree sums ----
        int e0 = b * CE, e1 = e0 + CE;
        for (int half = 0; half < 2; ++half) {
            int lo = half * HALFN;
            for (int i = threadIdx.x; i < HALFN / 2; i += 256) { scnt[i] = 0; sdeg[i] = 0; }
            __syncthreads();
            for (int e = e0 + threadIdx.x; e < e1; e += 256) {
                int r = ei[e];
                int c = ei[E + e];
                int ci = c - lo;
                if ((unsigned)ci < HALFN) atomicAdd(&scnt[ci >> 1], 1u << ((ci & 1) * 16));
                int ri = r - lo;
                if ((unsigned)ri < HALFN) {
                    float w = (r == c) ? 0.0f : ew[e];
                    uint32_t q = (uint32_t)(w * 1024.0f + 0.5f);
                    atomicAdd(&sdeg[ri >> 1], q << ((ri & 1) * 16));
                }
            }
            __syncthreads();
            for (int i = threadIdx.x; i < HALFN; i += 256) {
                cnt_h[(size_t)b * N + lo + i]  = (u16)((scnt[i >> 1] >> ((i & 1) * 16)) & 0xffffu);
                degq_h[(size_t)b * N + lo + i] = (u16)((sdeg[i >> 1] >> ((i & 1) * 16)) & 0xffffu);
            }
            __syncthreads();
        }
    } else {
        // ---- conversions: W1->W1t, W2->W2t, x->A1 slice0 ----
        int i = (b - NC) * 256 + threadIdx.x;
        const int S1 = 512 * 256;
        const int S2 = 4 * 256 * 128;
        const int SX = NNODES * 128;
        if (i < S1) {
            int k = i / 256, n = i - k * 256;
            W1t[(size_t)n * 512 + k] = f2bf(W1[i]);
        } else if (i < S1 + S2) {
            int j = i - S1;
            int kc = j / (256 * 128);
            int rem = j - kc * 256 * 128;
            int ci = rem / 128, co = rem - ci * 128;
            W2t[(size_t)(kc * 128 + co) * 256 + ci] = f2bf(W2[j]);
        } else if (i < S1 + S2 + SX) {
            int j = i - S1 - S2;
            int n = j >> 7, f = j & 127;
            A1[(size_t)n * 512 + f] = f2bf(x[j]);
        }
    }
}

// fused: per-node totals + dis + per-(chunk,node) fill-base deltas, one cnt_h sweep.
// baseD delta is independent of rowptr (prefix over chunks only).
__global__ void reduce_dis_base(const u16* __restrict__ cnt_h, const u16* __restrict__ degq_h,
                                int* __restrict__ tot, float* __restrict__ dis,
                                u16* __restrict__ baseD, int N) {
    int i = blockIdx.x * blockDim.x + threadIdx.x;
    if (i >= N) return;
    int t = 0;
    uint32_t dq = 0;
#pragma unroll 8
    for (int c = 0; c < NC; ++c) {
        baseD[(size_t)c * N + i] = (u16)t;
        t  += cnt_h[(size_t)c * N + i];
        dq += degq_h[(size_t)c * N + i];
    }
    tot[i] = t;
    float d = (float)dq * (1.0f / 1024.0f);
    dis[i] = (d > 0.0f) ? rsqrtf(d) : 0.0f;
}

__global__ void scan_kernel(const int* __restrict__ tot, int* __restrict__ rowptr, int N) {
    __shared__ int sums[256];
    int t = threadIdx.x;
    int per = (N + 255) / 256;
    int s0 = t * per, s1 = min(s0 + per, N);
    int s = 0;
    for (int i = s0; i < s1; ++i) s += tot[i];
    sums[t] = s;
    __syncthreads();
    if (t == 0) {
        int run = 0;
        for (int i = 0; i < 256; ++i) { int v = sums[i]; sums[i] = run; run += v; }
        rowptr[N] = run;
    }
    __syncthreads();
    int run = sums[t];
    for (int i = s0; i < s1; ++i) { rowptr[i] = run; run += tot[i]; }
}

// fill CSC: packed 4-byte records (src u16 | bf16 weight << 16)
__launch_bounds__(256)
__global__ void fill_kernel(const int* __restrict__ ei, const float* __restrict__ ew,
                            const float* __restrict__ dis, const int* __restrict__ rowptr,
                            const u16* __restrict__ baseD,
                            uint32_t* __restrict__ erec, int E, int N) {
    __shared__ uint32_t srank[NNODES / 2];  // 40 KB
    int chunk = blockIdx.x;
    int e0 = chunk * CE, e1 = e0 + CE;
    for (int i = threadIdx.x; i < NNODES / 2; i += 256) srank[i] = 0;
    __syncthreads();
    for (int e = e0 + threadIdx.x; e < e1; e += 256) {
        int r = ei[e];
        int c = ei[E + e];
        float w = (r == c) ? 0.0f : ew[e];
        float wn = -(dis[r] * w * dis[c]);   // * (2/lambda_max) = *1
        int sh = (c & 1) * 16;
        uint32_t old = atomicAdd(&srank[c >> 1], 1u << sh);
        int rank = (old >> sh) & 0xffff;
        int pos = rowptr[c] + (int)baseD[(size_t)chunk * N + c] + rank;
        erec[pos] = (uint32_t)r | ((uint32_t)f2bf(wn) << 16);
    }
}

// ---------------- general spmm (CSC gather, F=128, 16 threads/node, uint4, unroll-4) ----------------
// tout[n] = s * sum_p w[p]*tin[src[p]] + c1*t1[n] + c2*t2[n]  (+bias, relu if flag)
__launch_bounds__(256)
__global__ void spmm_cl(const int* __restrict__ rowptr, const uint32_t* __restrict__ erec,
                        const u16* __restrict__ tin, int ldi,
                        const u16* __restrict__ t1, int ld1, float c1,
                        const u16* __restrict__ t2, int ld2, float c2,
                        u16* __restrict__ tout, int ldo,
                        const float* __restrict__ bias, int doReluBias,
                        int N, float s) {
    int gid = blockIdx.x * blockDim.x + threadIdx.x;
    int n = gid >> 4;
    if (n >= N) return;
    int f = (gid & 15) << 3;
    int p = rowptr[n], pe = rowptr[n + 1];
    float acc[8] = {};
    for (; p + 3 < pe; p += 4) {
        uint32_t r0 = erec[p], r1 = erec[p + 1], r2 = erec[p + 2], r3 = erec[p + 3];
        uint4 v0 = *(const uint4*)(tin + (size_t)(r0 & 0xffffu) * ldi + f);
        uint4 v1 = *(const uint4*)(tin + (size_t)(r1 & 0xffffu) * ldi + f);
        uint4 v2 = *(const uint4*)(tin + (size_t)(r2 & 0xffffu) * ldi + f);
        uint4 v3 = *(const uint4*)(tin + (size_t)(r3 & 0xffffu) * ldi + f);
        float w0 = bf2f((u16)(r0 >> 16)), w1 = bf2f((u16)(r1 >> 16));
        float w2 = bf2f((u16)(r2 >> 16)), w3 = bf2f((u16)(r3 >> 16));
        float fa[8];
        unpack8(v0, fa);
#pragma unroll
        for (int q = 0; q < 8; ++q) acc[q] += w0 * fa[q];
        unpack8(v1, fa);
#pragma unroll
        for (int q = 0; q < 8; ++q) acc[q] += w1 * fa[q];
        unpack8(v2, fa);
#pragma unroll
        for (int q = 0; q < 8; ++q) acc[q] += w2 * fa[q];
        unpack8(v3, fa);
#pragma unroll
        for (int q = 0; q < 8; ++q) acc[q] += w3 * fa[q];
    }
    for (; p < pe; ++p) {
        uint32_t r0 = erec[p];
        uint4 v0 = *(const uint4*)(tin + (size_t)(r0 & 0xffffu) * ldi + f);
        float w0 = bf2f((u16)(r0 >> 16));
        float fa[8];
        unpack8(v0, fa);
#pragma unroll
        for (int q = 0; q < 8; ++q) acc[q] += w0 * fa[q];
    }
#pragma unroll
    for (int q = 0; q < 8; ++q) acc[q] *= s;
    if (t1) {
        uint4 v = *(const uint4*)(t1 + (size_t)n * ld1 + f);
        float fv[8]; unpack8(v, fv);
#pragma unroll
        for (int q = 0; q < 8; ++q) acc[q] += c1 * fv[q];
    }
    if (t2) {
        uint4 v = *(const uint4*)(t2 + (size_t)n * ld2 + f);
        float fv[8]; unpack8(v, fv);
#pragma unroll
        for (int q = 0; q < 8; ++q) acc[q] += c2 * fv[q];
    }
    if (doReluBias) {
#pragma unroll
        for (int q = 0; q < 8; ++q) acc[q] = fmaxf(acc[q] + bias[f + q], 0.0f);
    }
    uint4 o;
    o.x = f2bf2(acc[0], acc[1]);
    o.y = f2bf2(acc[2], acc[3]);
    o.z = f2bf2(acc[4], acc[5]);
    o.w = f2bf2(acc[6], acc[7]);
    *(uint4*)(tout + (size_t)n * ldo + f) = o;
}

// ---------------- bf16 MFMA GEMM, 128x128 tile (+optional fused BN column stats) ----------------

typedef __attribute__((ext_vector_type(8))) short short8;
typedef __attribute__((ext_vector_type(4))) float floatx4;

#define GBM 128
#define GBN 128
#define GBK 64

__launch_bounds__(256)
__global__ void gemm_mfma(const u16* __restrict__ A, const u16* __restrict__ Bt,
                          const float* __restrict__ bias, void* __restrict__ Cout,
                          float* __restrict__ ssum, float* __restrict__ ssq,
                          int M, int N, int K, int doRelu, int outBf) {
    __shared__ __align__(16) u16 As[GBM][GBK + 8];   // stride 144 B: 2-way LDS aliasing only
    __shared__ __align__(16) u16 Bs[GBN][GBK + 8];
    __shared__ float colsum[GBN], colsq[GBN];

    int tid = threadIdx.x;
    int lane = tid & 63;
    int wave = tid >> 6;
    int wm = (wave & 1) * 64;
    int wn = (wave >> 1) * 64;
    int rowBase = blockIdx.x * GBM;
    int colBase = blockIdx.y * GBN;

    floatx4 acc[4][4];
#pragma unroll
    for (int i = 0; i < 4; ++i)
#pragma unroll
        for (int j = 0; j < 4; ++j) {
            acc[i][j][0] = 0.f; acc[i][j][1] = 0.f; acc[i][j][2] = 0.f; acc[i][j][3] = 0.f;
        }

    int sr = tid >> 3;             // 0..31
    int sc = (tid & 7) * 8;        // 0..56

    for (int k0 = 0; k0 < K; k0 += GBK) {
#pragma unroll
        for (int h = 0; h < 4; ++h) {
            int r = sr + h * 32;
            int gm = rowBase + r;
            uint4 v = make_uint4(0, 0, 0, 0);
            if (gm < M) v = *(const uint4*)(A + (size_t)gm * K + k0 + sc);
            *(uint4*)&As[r][sc] = v;
            int gn = colBase + r;                    // N multiple of 128 -> no guard
            uint4 w = *(const uint4*)(Bt + (size_t)gn * K + k0 + sc);
            *(uint4*)&Bs[r][sc] = w;
        }
        __syncthreads();

        int mrow = lane & 15;
        int kq = (lane >> 4) * 8;
#pragma unroll
        for (int kk = 0; kk < GBK; kk += 32) {
            short8 af[4], bfr[4];
#pragma unroll
            for (int i = 0; i < 4; ++i) af[i] = *(const short8*)&As[wm + i * 16 + mrow][kk + kq];
#pragma unroll
            for (int j = 0; j < 4; ++j) bfr[j] = *(const short8*)&Bs[wn + j * 16 + mrow][kk + kq];
#pragma unroll
            for (int i = 0; i < 4; ++i)
#pragma unroll
                for (int j = 0; j < 4; ++j)
                    acc[i][j] = __builtin_amdgcn_mfma_f32_16x16x32_bf16(af[i], bfr[j], acc[i][j], 0, 0, 0);
        }
        __syncthreads();
    }

    if (ssum) {
        if (tid < GBN) { colsum[tid] = 0.f; colsq[tid] = 0.f; }
        __syncthreads();
    }

    int cn0 = colBase + wn + (lane & 15);
    int rq = (lane >> 4) * 4;
    float* Cf = (float*)Cout;
    u16*   Cb = (u16*)Cout;
#pragma unroll
    for (int j = 0; j < 4; ++j) {
        float ps = 0.f, pq = 0.f;
        int n = cn0 + j * 16;
#pragma unroll
        for (int i = 0; i < 4; ++i) {
#pragma unroll
            for (int r = 0; r < 4; ++r) {
                int m = rowBase + wm + i * 16 + rq + r;
                if (m >= M) continue;
                float v = acc[i][j][r];
                if (bias) v += bias[n];
                if (doRelu) v = fmaxf(v, 0.0f);
                if (outBf) {
                    u16 bb = f2bf(v);
                    Cb[(size_t)m * N + n] = bb;
                    if (ssum) { float vb = bf2f(bb); ps += vb; pq += vb * vb; }
                } else {
                    Cf[(size_t)m * N + n] = v;
                }
            }
        }
        if (ssum) {
            int lc = wn + j * 16 + (lane & 15);
            atomicAdd(&colsum[lc], ps);
            atomicAdd(&colsq[lc], pq);
        }
    }
    if (ssum) {
        __syncthreads();
        if (tid < GBN) {
            atomicAdd(&ssum[colBase + tid], colsum[tid]);
            atomicAdd(&ssq[colBase + tid], colsq[tid]);
        }
    }
}

// ---------------- batchnorm stats (BN2 only; BN1 fused into GEMM1) ----------------

#define BN_ROWS 64
__global__ void bn_stats_bf(const u16* __restrict__ h, int N, int C,
                            float* __restrict__ sums, float* __restrict__ sumsq) {
    int c = threadIdx.x;
    int r0 = blockIdx.x * BN_ROWS;
    int r1 = min(r0 + BN_ROWS, N);
    float s = 0.f, q = 0.f;
    for (int r = r0; r < r1; ++r) {
        float v = bf2f(h[(size_t)r * C + c]);
        s += v;
        q += v * v;
    }
    atomicAdd(&sums[c], s);
    atomicAdd(&sumsq[c], q);
}

// fold BN1 into W2t (in place); bn_final computed inline per block.
__launch_bounds__(256)
__global__ void fold_w2(u16* __restrict__ W2t, const float* __restrict__ sums,
                        const float* __restrict__ sumsq, const float* __restrict__ gamma,
                        const float* __restrict__ beta, float* __restrict__ rowvec, float invN) {
    __shared__ float red[4];
    int n = blockIdx.x;
    int k = threadIdx.x;
    float m = sums[k] * invN;
    float var = sumsq[k] * invN - m * m;
    float sc = gamma[k] / sqrtf(var + BN_EPS);
    float sh = beta[k] - m * sc;
    float wf = bf2f(W2t[(size_t)n * 256 + k]);
    W2t[(size_t)n * 256 + k] = f2bf(wf * sc);
    float part = sh * wf;
#pragma unroll
    for (int off = 32; off > 0; off >>= 1) part += __shfl_down(part, off);
    if ((k & 63) == 0) red[k >> 6] = part;
    __syncthreads();
    if (k == 0) rowvec[n] = red[0] + red[1] + red[2] + red[3];
}

// ---------------- final linear with inline BN2 fold (bf16 input) ----------------

__global__ void final_linear_bn(const u16* __restrict__ g, const float* __restrict__ Wlin,
                                const float* __restrict__ blin, const float* __restrict__ sums,
                                const float* __restrict__ sumsq, const float* __restrict__ gamma,
                                const float* __restrict__ beta, float* __restrict__ out,
                                int N, float invN) {
    __shared__ float Ws[OUT_F * CL2_F];
    __shared__ float bs[OUT_F];
    __shared__ float scs[CL2_F], shs[CL2_F];
    for (int i = threadIdx.x; i < OUT_F * CL2_F; i += 256) Ws[i] = Wlin[i];
    if (threadIdx.x < OUT_F) bs[threadIdx.x] = blin[threadIdx.x];
    if (threadIdx.x < CL2_F) {
        int c = threadIdx.x;
        float m = sums[c] * invN;
        float var = sumsq[c] * invN - m * m;
        float sc = gamma[c] / sqrtf(var + BN_EPS);
        scs[c] = sc;
        shs[c] = beta[c] - m * sc;
    }
    __syncthreads();
    int idx = blockIdx.x * 256 + threadIdx.x;
    if (idx >= N * OUT_F) return;
    int n = idx / OUT_F, o = idx - n * OUT_F;
    const u16* gr = g + (size_t)n * CL2_F;
    const float* wr = Ws + o * CL2_F;
    float acc = 0.f;
#pragma unroll 8
    for (int f = 0; f < CL2_F; ++f) acc += (bf2f(gr[f]) * scs[f] + shs[f]) * wr[f];
    out[idx] = acc + bs[o];
}

// ---------------- host launch ----------------

extern "C" void kernel_launch(void* const* d_in, const int* in_sizes, int n_in,
                              void* d_out, int out_size, void* d_ws, size_t ws_size,
                              hipStream_t stream) {
    const float* x      = (const float*)d_in[0];
    const int*   ei     = (const int*)d_in[1];
    const float* ew     = (const float*)d_in[2];
    const float* W1     = (const float*)d_in[3];
    const float* b1     = (const float*)d_in[4];
    const float* W2     = (const float*)d_in[5];
    const float* b2     = (const float*)d_in[6];
    const float* gamma1 = (const float*)d_in[7];
    const float* beta1  = (const float*)d_in[8];
    const float* gamma2 = (const float*)d_in[9];
    const float* beta2  = (const float*)d_in[10];
    const float* Wlin   = (const float*)d_in[11];
    const float* blin   = (const float*)d_in[12];
    float* out = (float*)d_out;

    const int N = NNODES, E = NEDGES;

    // workspace (~80.2 MB). baseD is NC*N u16 = 10.24 MB — full extent, no overlap.
    char* base = (char*)d_ws;
    u16*     cnt_h  = (u16*)    (base + 0);           // NC*N u16 = 10.24 MB
    u16*     degq_h = (u16*)    (base + 10240000);    // NC*N u16 = 10.24 MB
    u16*     baseD  = (u16*)    (base + 20480000);    // NC*N u16 = 10.24 MB (ends 30,720,000)
    u16*     A1     = (u16*)    (base + 30720000);    // N*512 bf16 = 20.48 MB
    u16*     Hc     = A1;                             // aliased (A1 dead after GEMM1)
    u16*     h1bf   = (u16*)    (base + 51200000);    // N*256 bf16 = 10.24 MB
    u16*     pbuf   = (u16*)    (base + 61440000);    // N*128 bf16 = 5.12 MB
    u16*     bb2    = (u16*)    (base + 66560000);    // N*128 bf16
    u16*     bb1    = (u16*)    (base + 71680000);    // N*128 bf16
    uint32_t* erec  = (uint32_t*)(base + 76800000);   // E*4 = 2.56 MB
    u16*     W1t    = (u16*)    (base + 79360000);    // 256*512 bf16 = 262144
    u16*     W2t    = (u16*)    (base + 79622144);    // 512*256 bf16 = 262144
    float*   rowvec = (float*)  (base + 79884288);    // 512 f32
    int*     rowptr = (int*)    (base + 79886336);    // N+1
    int*     tot    = (int*)    (base + 79966352);    // N
    float*   dis    = (float*)  (base + 80046352);    // N
    float*   bns1   = (float*)  (base + 80126352);    // 256 (BN1 sums)
    float*   bnq1    = bns1 + 256;                    // 256 (BN1 sumsq)
    float*   bns2    = bnq1 + 256;                    // 256 (BN2 sums; 128 used)
    float*   bnq2    = bns2 + 256;                    // 256 (BN2 sumsq)

    dim3 blk(256);

    // --- zero all BN stat buffers once (GEMM1 accumulates into bns1/bnq1) ---
    hipMemsetAsync(bns1, 0, 4 * 256 * sizeof(float), stream);

    // --- fused: CSC histograms + all dtype conversions in one launch ---
    build_hist_conv<<<dim3(NC + (CONVN + 255) / 256), blk, 0, stream>>>(
        ei, ew, cnt_h, degq_h, W1, W1t, W2, W2t, x, A1, E, N);
    // fused: totals + dis + baseD deltas in one cnt_h/degq_h sweep
    reduce_dis_base<<<dim3((N + 255) / 256), blk, 0, stream>>>(cnt_h, degq_h, tot, dis, baseD, N);
    scan_kernel<<<dim3(1), blk, 0, stream>>>(tot, rowptr, N);
    fill_kernel<<<dim3(NC), blk, 0, stream>>>(ei, ew, dis, rowptr, baseD, erec, E, N);

    dim3 gS(((N << 4) + 255) / 256);   // spmm grid: 16 threads/node

    // --- layer 1: A1 = [x|T1|T2|T3] bf16, ld 512 ---
    spmm_cl<<<gS, blk, 0, stream>>>(rowptr, erec, A1 + 0,   512, nullptr,  512, 0.f,
                                    nullptr, 512, 0.f, A1 + 128, 512, nullptr, 0, N, 1.0f);
    spmm_cl<<<gS, blk, 0, stream>>>(rowptr, erec, A1 + 128, 512, A1 + 0,   512, -1.f,
                                    nullptr, 512, 0.f, A1 + 256, 512, nullptr, 0, N, 2.0f);
    spmm_cl<<<gS, blk, 0, stream>>>(rowptr, erec, A1 + 256, 512, A1 + 128, 512, -1.f,
                                    nullptr, 512, 0.f, A1 + 384, 512, nullptr, 0, N, 2.0f);

    // --- GEMM1: h1bf = relu(A1 @ W1 + b1) bf16, fused BN1 column stats ---
    gemm_mfma<<<dim3((N + GBM - 1) / GBM, CL1_F / GBN), blk, 0, stream>>>(
        A1, W1t, b1, h1bf, bns1, bnq1, N, CL1_F, 512, 1, 1);

    // --- fold BN1 into W2t + rowvec ---
    fold_w2<<<dim3(512), dim3(256), 0, stream>>>(W2t, bns1, bnq1, gamma1, beta1, rowvec, 1.0f / N);

    // --- GEMM2: Hc = h1bf @ W2t' + rowvec  [M=20000, N=512, K=256] bf16 out ---
    gemm_mfma<<<dim3((N + GBM - 1) / GBM, 512 / GBN), blk, 0, stream>>>(
        h1bf, W2t, rowvec, Hc, nullptr, nullptr, N, 512, 256, 0, 1);

    // --- layer 2 via Clenshaw (F=128 spmms) ---
    spmm_cl<<<gS, blk, 0, stream>>>(rowptr, erec, Hc + 384, 512, Hc + 256, 512, 1.f,
                                    nullptr, 512, 0.f, bb2, 128, nullptr, 0, N, 2.0f);
    spmm_cl<<<gS, blk, 0, stream>>>(rowptr, erec, bb2, 128, Hc + 384, 512, -1.f,
                                    Hc + 128, 512, 1.f, bb1, 128, nullptr, 0, N, 2.0f);
    spmm_cl<<<gS, blk, 0, stream>>>(rowptr, erec, bb1, 128, bb2, 128, -1.f,
                                    Hc + 0, 512, 1.f, pbuf, 128, b2, 1, N, 1.0f);

    // --- BN2 stats ---
    bn_stats_bf<<<dim3((N + BN_ROWS - 1) / BN_ROWS), dim3(CL2_F), 0, stream>>>(pbuf, N, CL2_F, bns2, bnq2);

    // --- final linear with inline BN2 fold ---
    final_linear_bn<<<dim3((N * OUT_F + 255) / 256), blk, 0, stream>>>(
        pbuf, Wlin, blin, bns2, bnq2, gamma2, beta2, out, N, 1.0f / N);
}

// Round 13
// 381.413 us; speedup vs baseline: 1.1840x; 1.0040x over previous
//
#include <hip/hip_runtime.h>
#include <cstdint>
#include <cstddef>

// Problem constants (match reference)
#define NNODES 20000
#define NEDGES 640000
#define IN_F   128
#define CL1_F  256
#define CL2_F  128
#define OUT_F  10
#define BN_EPS 1e-5f

#define NC     256                // edge chunks for cnt/fill (2500 edges each)
#define CE     (NEDGES / NC)
#define HALFN  10000              // node half-range for LDS histograms

// conv workload appended to the hist launch
#define CONVN  (512 * 256 + 4 * 256 * 128 + NNODES * 128)

typedef unsigned short u16;

// ---------------- bf16 helpers ----------------

__device__ __forceinline__ float bf2f(u16 u) {
    union { uint32_t i; float f; } v; v.i = ((uint32_t)u) << 16; return v.f;
}
__device__ __forceinline__ u16 f2bf(float f) {
    union { float f; uint32_t i; } v; v.f = f;
    uint32_t r = v.i + 0x7fffu + ((v.i >> 16) & 1u);   // RNE
    return (u16)(r >> 16);
}
__device__ __forceinline__ void bf2x2(uint32_t u, float& lo, float& hi) {
    union { uint32_t i; float f; } a, b;
    a.i = u << 16; b.i = u & 0xffff0000u;
    lo = a.f; hi = b.f;
}
__device__ __forceinline__ uint32_t f2bf2(float lo, float hi) {
    return (uint32_t)f2bf(lo) | ((uint32_t)f2bf(hi) << 16);
}
__device__ __forceinline__ void unpack8(uint4 v, float* o) {
    bf2x2(v.x, o[0], o[1]); bf2x2(v.y, o[2], o[3]);
    bf2x2(v.z, o[4], o[5]); bf2x2(v.w, o[6], o[7]);
}

// ---------------- fused: CSC hist (blocks 0..NC) + weight/x conversion (rest) ----------------

__launch_bounds__(256)
__global__ void build_hist_conv(const int* __restrict__ ei, const float* __restrict__ ew,
                                u16* __restrict__ cnt_h, u16* __restrict__ degq_h,
                                const float* __restrict__ W1, u16* __restrict__ W1t,
                                const float* __restrict__ W2, u16* __restrict__ W2t,
                                const float* __restrict__ x, u16* __restrict__ A1,
                                int E, int N) {
    __shared__ uint32_t scnt[HALFN / 2];   // 20 KB
    __shared__ uint32_t sdeg[HALFN / 2];   // 20 KB
    int b = blockIdx.x;
    if (b < NC) {
        // ---- per-chunk histogram: dst counts + fixed-point src-degree sums ----
        int e0 = b * CE, e1 = e0 + CE;
        for (int half = 0; half < 2; ++half) {
            int lo = half * HALFN;
            for (int i = threadIdx.x; i < HALFN / 2; i += 256) { scnt[i] = 0; sdeg[i] = 0; }
            __syncthreads();
            for (int e = e0 + threadIdx.x; e < e1; e += 256) {
                int r = ei[e];
                int c = ei[E + e];
                int ci = c - lo;
                if ((unsigned)ci < HALFN) atomicAdd(&scnt[ci >> 1], 1u << ((ci & 1) * 16));
                int ri = r - lo;
                if ((unsigned)ri < HALFN) {
                    float w = (r == c) ? 0.0f : ew[e];
                    uint32_t q = (uint32_t)(w * 1024.0f + 0.5f);
                    atomicAdd(&sdeg[ri >> 1], q << ((ri & 1) * 16));
                }
            }
            __syncthreads();
            for (int i = threadIdx.x; i < HALFN; i += 256) {
                cnt_h[(size_t)b * N + lo + i]  = (u16)((scnt[i >> 1] >> ((i & 1) * 16)) & 0xffffu);
                degq_h[(size_t)b * N + lo + i] = (u16)((sdeg[i >> 1] >> ((i & 1) * 16)) & 0xffffu);
            }
            __syncthreads();
        }
    } else {
        // ---- conversions: W1->W1t, W2->W2t, x->A1 slice0 ----
        int i = (b - NC) * 256 + threadIdx.x;
        const int S1 = 512 * 256;
        const int S2 = 4 * 256 * 128;
        const int SX = NNODES * 128;
        if (i < S1) {
            int k = i / 256, n = i - k * 256;
            W1t[(size_t)n * 512 + k] = f2bf(W1[i]);
        } else if (i < S1 + S2) {
            int j = i - S1;
            int kc = j / (256 * 128);
            int rem = j - kc * 256 * 128;
            int ci = rem / 128, co = rem - ci * 128;
            W2t[(size_t)(kc * 128 + co) * 256 + ci] = f2bf(W2[j]);
        } else if (i < S1 + S2 + SX) {
            int j = i - S1 - S2;
            int n = j >> 7, f = j & 127;
            A1[(size_t)n * 512 + f] = f2bf(x[j]);
        }
    }
}

// fused: per-node totals + dis + per-(chunk,node) fill-base deltas, one cnt_h sweep.
__global__ void reduce_dis_base(const u16* __restrict__ cnt_h, const u16* __restrict__ degq_h,
                                int* __restrict__ tot, float* __restrict__ dis,
                                u16* __restrict__ baseD, int N) {
    int i = blockIdx.x * blockDim.x + threadIdx.x;
    if (i >= N) return;
    int t = 0;
    uint32_t dq = 0;
#pragma unroll 8
    for (int c = 0; c < NC; ++c) {
        baseD[(size_t)c * N + i] = (u16)t;
        t  += cnt_h[(size_t)c * N + i];
        dq += degq_h[(size_t)c * N + i];
    }
    tot[i] = t;
    float d = (float)dq * (1.0f / 1024.0f);
    dis[i] = (d > 0.0f) ? rsqrtf(d) : 0.0f;
}

__global__ void scan_kernel(const int* __restrict__ tot, int* __restrict__ rowptr, int N) {
    __shared__ int sums[256];
    int t = threadIdx.x;
    int per = (N + 255) / 256;
    int s0 = t * per, s1 = min(s0 + per, N);
    int s = 0;
    for (int i = s0; i < s1; ++i) s += tot[i];
    sums[t] = s;
    __syncthreads();
    if (t == 0) {
        int run = 0;
        for (int i = 0; i < 256; ++i) { int v = sums[i]; sums[i] = run; run += v; }
        rowptr[N] = run;
    }
    __syncthreads();
    int run = sums[t];
    for (int i = s0; i < s1; ++i) { rowptr[i] = run; run += tot[i]; }
}

// fill CSC: packed 4-byte records (src u16 | bf16 weight << 16)
__launch_bounds__(256)
__global__ void fill_kernel(const int* __restrict__ ei, const float* __restrict__ ew,
                            const float* __restrict__ dis, const int* __restrict__ rowptr,
                            const u16* __restrict__ baseD,
                            uint32_t* __restrict__ erec, int E, int N) {
    __shared__ uint32_t srank[NNODES / 2];  // 40 KB
    int chunk = blockIdx.x;
    int e0 = chunk * CE, e1 = e0 + CE;
    for (int i = threadIdx.x; i < NNODES / 2; i += 256) srank[i] = 0;
    __syncthreads();
    for (int e = e0 + threadIdx.x; e < e1; e += 256) {
        int r = ei[e];
        int c = ei[E + e];
        float w = (r == c) ? 0.0f : ew[e];
        float wn = -(dis[r] * w * dis[c]);   // * (2/lambda_max) = *1
        int sh = (c & 1) * 16;
        uint32_t old = atomicAdd(&srank[c >> 1], 1u << sh);
        int rank = (old >> sh) & 0xffff;
        int pos = rowptr[c] + (int)baseD[(size_t)chunk * N + c] + rank;
        erec[pos] = (uint32_t)r | ((uint32_t)f2bf(wn) << 16);
    }
}

// ---------------- general spmm (CSC gather, F=128, 16 threads/node, uint4, unroll-4) ----------------
__launch_bounds__(256)
__global__ void spmm_cl(const int* __restrict__ rowptr, const uint32_t* __restrict__ erec,
                        const u16* __restrict__ tin, int ldi,
                        const u16* __restrict__ t1, int ld1, float c1,
                        const u16* __restrict__ t2, int ld2, float c2,
                        u16* __restrict__ tout, int ldo,
                        const float* __restrict__ bias, int doReluBias,
                        int N, float s) {
    int gid = blockIdx.x * blockDim.x + threadIdx.x;
    int n = gid >> 4;
    if (n >= N) return;
    int f = (gid & 15) << 3;
    int p = rowptr[n], pe = rowptr[n + 1];
    float acc[8] = {};
    for (; p + 3 < pe; p += 4) {
        uint32_t r0 = erec[p], r1 = erec[p + 1], r2 = erec[p + 2], r3 = erec[p + 3];
        uint4 v0 = *(const uint4*)(tin + (size_t)(r0 & 0xffffu) * ldi + f);
        uint4 v1 = *(const uint4*)(tin + (size_t)(r1 & 0xffffu) * ldi + f);
        uint4 v2 = *(const uint4*)(tin + (size_t)(r2 & 0xffffu) * ldi + f);
        uint4 v3 = *(const uint4*)(tin + (size_t)(r3 & 0xffffu) * ldi + f);
        float w0 = bf2f((u16)(r0 >> 16)), w1 = bf2f((u16)(r1 >> 16));
        float w2 = bf2f((u16)(r2 >> 16)), w3 = bf2f((u16)(r3 >> 16));
        float fa[8];
        unpack8(v0, fa);
#pragma unroll
        for (int q = 0; q < 8; ++q) acc[q] += w0 * fa[q];
        unpack8(v1, fa);
#pragma unroll
        for (int q = 0; q < 8; ++q) acc[q] += w1 * fa[q];
        unpack8(v2, fa);
#pragma unroll
        for (int q = 0; q < 8; ++q) acc[q] += w2 * fa[q];
        unpack8(v3, fa);
#pragma unroll
        for (int q = 0; q < 8; ++q) acc[q] += w3 * fa[q];
    }
    for (; p < pe; ++p) {
        uint32_t r0 = erec[p];
        uint4 v0 = *(const uint4*)(tin + (size_t)(r0 & 0xffffu) * ldi + f);
        float w0 = bf2f((u16)(r0 >> 16));
        float fa[8];
        unpack8(v0, fa);
#pragma unroll
        for (int q = 0; q < 8; ++q) acc[q] += w0 * fa[q];
    }
#pragma unroll
    for (int q = 0; q < 8; ++q) acc[q] *= s;
    if (t1) {
        uint4 v = *(const uint4*)(t1 + (size_t)n * ld1 + f);
        float fv[8]; unpack8(v, fv);
#pragma unroll
        for (int q = 0; q < 8; ++q) acc[q] += c1 * fv[q];
    }
    if (t2) {
        uint4 v = *(const uint4*)(t2 + (size_t)n * ld2 + f);
        float fv[8]; unpack8(v, fv);
#pragma unroll
        for (int q = 0; q < 8; ++q) acc[q] += c2 * fv[q];
    }
    if (doReluBias) {
#pragma unroll
        for (int q = 0; q < 8; ++q) acc[q] = fmaxf(acc[q] + bias[f + q], 0.0f);
    }
    uint4 o;
    o.x = f2bf2(acc[0], acc[1]);
    o.y = f2bf2(acc[2], acc[3]);
    o.z = f2bf2(acc[4], acc[5]);
    o.w = f2bf2(acc[6], acc[7]);
    *(uint4*)(tout + (size_t)n * ldo + f) = o;
}

// ---------------- bf16 MFMA GEMM, 64x64 tile (+optional fused BN column stats) ----------------
// 64x64 tile: GEMM1 grid = 313*4 = 1252 blocks (vs 314 at 128-tile) -> latency hiding.
// LDS 19 KB -> 8 blocks/CU. // R12 PMC: 128-tile had Occupancy 10%, MfmaUtil 3.6% (grid-starved).

typedef __attribute__((ext_vector_type(8))) short short8;
typedef __attribute__((ext_vector_type(4))) float floatx4;

#define GBM 64
#define GBN 64
#define GBK 64

__launch_bounds__(256)
__global__ void gemm_mfma(const u16* __restrict__ A, const u16* __restrict__ Bt,
                          const float* __restrict__ bias, void* __restrict__ Cout,
                          float* __restrict__ ssum, float* __restrict__ ssq,
                          int M, int N, int K, int doRelu, int outBf) {
    __shared__ __align__(16) u16 As[GBM][GBK + 8];   // stride 144 B
    __shared__ __align__(16) u16 Bs[GBN][GBK + 8];
    __shared__ float colsum[GBN], colsq[GBN];

    int tid = threadIdx.x;
    int lane = tid & 63;
    int wave = tid >> 6;
    int wm = (wave & 1) * 32;
    int wn = (wave >> 1) * 32;
    int rowBase = blockIdx.x * GBM;
    int colBase = blockIdx.y * GBN;

    floatx4 acc[2][2];
#pragma unroll
    for (int i = 0; i < 2; ++i)
#pragma unroll
        for (int j = 0; j < 2; ++j) {
            acc[i][j][0] = 0.f; acc[i][j][1] = 0.f; acc[i][j][2] = 0.f; acc[i][j][3] = 0.f;
        }

    int sr = tid >> 3;             // 0..31
    int sc = (tid & 7) * 8;        // 0..56

    for (int k0 = 0; k0 < K; k0 += GBK) {
#pragma unroll
        for (int h = 0; h < 2; ++h) {
            int r = sr + h * 32;
            int gm = rowBase + r;
            uint4 v = make_uint4(0, 0, 0, 0);
            if (gm < M) v = *(const uint4*)(A + (size_t)gm * K + k0 + sc);
            *(uint4*)&As[r][sc] = v;
            int gn = colBase + r;                    // N multiple of 64 -> no guard
            uint4 w = *(const uint4*)(Bt + (size_t)gn * K + k0 + sc);
            *(uint4*)&Bs[r][sc] = w;
        }
        __syncthreads();

        int mrow = lane & 15;
        int kq = (lane >> 4) * 8;
#pragma unroll
        for (int kk = 0; kk < GBK; kk += 32) {
            short8 af[2], bfr[2];
#pragma unroll
            for (int i = 0; i < 2; ++i) af[i] = *(const short8*)&As[wm + i * 16 + mrow][kk + kq];
#pragma unroll
            for (int j = 0; j < 2; ++j) bfr[j] = *(const short8*)&Bs[wn + j * 16 + mrow][kk + kq];
#pragma unroll
            for (int i = 0; i < 2; ++i)
#pragma unroll
                for (int j = 0; j < 2; ++j)
                    acc[i][j] = __builtin_amdgcn_mfma_f32_16x16x32_bf16(af[i], bfr[j], acc[i][j], 0, 0, 0);
        }
        __syncthreads();
    }

    if (ssum) {
        if (tid < GBN) { colsum[tid] = 0.f; colsq[tid] = 0.f; }
        __syncthreads();
    }

    int cn0 = colBase + wn + (lane & 15);
    int rq = (lane >> 4) * 4;
    float* Cf = (float*)Cout;
    u16*   Cb = (u16*)Cout;
#pragma unroll
    for (int j = 0; j < 2; ++j) {
        float ps = 0.f, pq = 0.f;
        int n = cn0 + j * 16;
#pragma unroll
        for (int i = 0; i < 2; ++i) {
#pragma unroll
            for (int r = 0; r < 4; ++r) {
                int m = rowBase + wm + i * 16 + rq + r;
                if (m >= M) continue;
                float v = acc[i][j][r];
                if (bias) v += bias[n];
                if (doRelu) v = fmaxf(v, 0.0f);
                if (outBf) {
                    u16 bb = f2bf(v);
                    Cb[(size_t)m * N + n] = bb;
                    if (ssum) { float vb = bf2f(bb); ps += vb; pq += vb * vb; }
                } else {
                    Cf[(size_t)m * N + n] = v;
                }
            }
        }
        if (ssum) {
            int lc = wn + j * 16 + (lane & 15);
            atomicAdd(&colsum[lc], ps);
            atomicAdd(&colsq[lc], pq);
        }
    }
    if (ssum) {
        __syncthreads();
        if (tid < GBN) {
            atomicAdd(&ssum[colBase + tid], colsum[tid]);
            atomicAdd(&ssq[colBase + tid], colsq[tid]);
        }
    }
}

// ---------------- batchnorm stats (BN2 only; BN1 fused into GEMM1) ----------------

#define BN_ROWS 64
__global__ void bn_stats_bf(const u16* __restrict__ h, int N, int C,
                            float* __restrict__ sums, float* __restrict__ sumsq) {
    int c = threadIdx.x;
    int r0 = blockIdx.x * BN_ROWS;
    int r1 = min(r0 + BN_ROWS, N);
    float s = 0.f, q = 0.f;
    for (int r = r0; r < r1; ++r) {
        float v = bf2f(h[(size_t)r * C + c]);
        s += v;
        q += v * v;
    }
    atomicAdd(&sums[c], s);
    atomicAdd(&sumsq[c], q);
}

// fold BN1 into W2t (in place); bn_final computed inline per block.
__launch_bounds__(256)
__global__ void fold_w2(u16* __restrict__ W2t, const float* __restrict__ sums,
                        const float* __restrict__ sumsq, const float* __restrict__ gamma,
                        const float* __restrict__ beta, float* __restrict__ rowvec, float invN) {
    __shared__ float red[4];
    int n = blockIdx.x;
    int k = threadIdx.x;
    float m = sums[k] * invN;
    float var = sumsq[k] * invN - m * m;
    float sc = gamma[k] / sqrtf(var + BN_EPS);
    float sh = beta[k] - m * sc;
    float wf = bf2f(W2t[(size_t)n * 256 + k]);
    W2t[(size_t)n * 256 + k] = f2bf(wf * sc);
    float part = sh * wf;
#pragma unroll
    for (int off = 32; off > 0; off >>= 1) part += __shfl_down(part, off);
    if ((k & 63) == 0) red[k >> 6] = part;
    __syncthreads();
    if (k == 0) rowvec[n] = red[0] + red[1] + red[2] + red[3];
}

// ---------------- final linear with inline BN2 fold (bf16 input) ----------------

__global__ void final_linear_bn(const u16* __restrict__ g, const float* __restrict__ Wlin,
                                const float* __restrict__ blin, const float* __restrict__ sums,
                                const float* __restrict__ sumsq, const float* __restrict__ gamma,
                                const float* __restrict__ beta, float* __restrict__ out,
                                int N, float invN) {
    __shared__ float Ws[OUT_F * CL2_F];
    __shared__ float bs[OUT_F];
    __shared__ float scs[CL2_F], shs[CL2_F];
    for (int i = threadIdx.x; i < OUT_F * CL2_F; i += 256) Ws[i] = Wlin[i];
    if (threadIdx.x < OUT_F) bs[threadIdx.x] = blin[threadIdx.x];
    if (threadIdx.x < CL2_F) {
        int c = threadIdx.x;
        float m = sums[c] * invN;
        float var = sumsq[c] * invN - m * m;
        float sc = gamma[c] / sqrtf(var + BN_EPS);
        scs[c] = sc;
        shs[c] = beta[c] - m * sc;
    }
    __syncthreads();
    int idx = blockIdx.x * 256 + threadIdx.x;
    if (idx >= N * OUT_F) return;
    int n = idx / OUT_F, o = idx - n * OUT_F;
    const u16* gr = g + (size_t)n * CL2_F;
    const float* wr = Ws + o * CL2_F;
    float acc = 0.f;
#pragma unroll 8
    for (int f = 0; f < CL2_F; ++f) acc += (bf2f(gr[f]) * scs[f] + shs[f]) * wr[f];
    out[idx] = acc + bs[o];
}

// ---------------- host launch ----------------

extern "C" void kernel_launch(void* const* d_in, const int* in_sizes, int n_in,
                              void* d_out, int out_size, void* d_ws, size_t ws_size,
                              hipStream_t stream) {
    const float* x      = (const float*)d_in[0];
    const int*   ei     = (const int*)d_in[1];
    const float* ew     = (const float*)d_in[2];
    const float* W1     = (const float*)d_in[3];
    const float* b1     = (const float*)d_in[4];
    const float* W2     = (const float*)d_in[5];
    const float* b2     = (const float*)d_in[6];
    const float* gamma1 = (const float*)d_in[7];
    const float* beta1  = (const float*)d_in[8];
    const float* gamma2 = (const float*)d_in[9];
    const float* beta2  = (const float*)d_in[10];
    const float* Wlin   = (const float*)d_in[11];
    const float* blin   = (const float*)d_in[12];
    float* out = (float*)d_out;

    const int N = NNODES, E = NEDGES;

    // workspace (~80.2 MB). baseD is NC*N u16 = 10.24 MB — full extent, no overlap.
    char* base = (char*)d_ws;
    u16*     cnt_h  = (u16*)    (base + 0);           // NC*N u16 = 10.24 MB
    u16*     degq_h = (u16*)    (base + 10240000);    // NC*N u16 = 10.24 MB
    u16*     baseD  = (u16*)    (base + 20480000);    // NC*N u16 = 10.24 MB (ends 30,720,000)
    u16*     A1     = (u16*)    (base + 30720000);    // N*512 bf16 = 20.48 MB
    u16*     Hc     = A1;                             // aliased (A1 dead after GEMM1)
    u16*     h1bf   = (u16*)    (base + 51200000);    // N*256 bf16 = 10.24 MB
    u16*     pbuf   = (u16*)    (base + 61440000);    // N*128 bf16 = 5.12 MB
    u16*     bb2    = (u16*)    (base + 66560000);    // N*128 bf16
    u16*     bb1    = (u16*)    (base + 71680000);    // N*128 bf16
    uint32_t* erec  = (uint32_t*)(base + 76800000);   // E*4 = 2.56 MB
    u16*     W1t    = (u16*)    (base + 79360000);    // 256*512 bf16 = 262144
    u16*     W2t    = (u16*)    (base + 79622144);    // 512*256 bf16 = 262144
    float*   rowvec = (float*)  (base + 79884288);    // 512 f32
    int*     rowptr = (int*)    (base + 79886336);    // N+1
    int*     tot    = (int*)    (base + 79966352);    // N
    float*   dis    = (float*)  (base + 80046352);    // N
    float*   bns1   = (float*)  (base + 80126352);    // 256 (BN1 sums)
    float*   bnq1    = bns1 + 256;                    // 256 (BN1 sumsq)
    float*   bns2    = bnq1 + 256;                    // 256 (BN2 sums; 128 used)
    float*   bnq2    = bns2 + 256;                    // 256 (BN2 sumsq)

    dim3 blk(256);

    // --- zero all BN stat buffers once (GEMM1 accumulates into bns1/bnq1) ---
    hipMemsetAsync(bns1, 0, 4 * 256 * sizeof(float), stream);

    // --- fused: CSC histograms + all dtype conversions in one launch ---
    build_hist_conv<<<dim3(NC + (CONVN + 255) / 256), blk, 0, stream>>>(
        ei, ew, cnt_h, degq_h, W1, W1t, W2, W2t, x, A1, E, N);
    // fused: totals + dis + baseD deltas in one cnt_h/degq_h sweep
    reduce_dis_base<<<dim3((N + 255) / 256), blk, 0, stream>>>(cnt_h, degq_h, tot, dis, baseD, N);
    scan_kernel<<<dim3(1), blk, 0, stream>>>(tot, rowptr, N);
    fill_kernel<<<dim3(NC), blk, 0, stream>>>(ei, ew, dis, rowptr, baseD, erec, E, N);

    dim3 gS(((N << 4) + 255) / 256);   // spmm grid: 16 threads/node

    // --- layer 1: A1 = [x|T1|T2|T3] bf16, ld 512 ---
    spmm_cl<<<gS, blk, 0, stream>>>(rowptr, erec, A1 + 0,   512, nullptr,  512, 0.f,
                                    nullptr, 512, 0.f, A1 + 128, 512, nullptr, 0, N, 1.0f);
    spmm_cl<<<gS, blk, 0, stream>>>(rowptr, erec, A1 + 128, 512, A1 + 0,   512, -1.f,
                                    nullptr, 512, 0.f, A1 + 256, 512, nullptr, 0, N, 2.0f);
    spmm_cl<<<gS, blk, 0, stream>>>(rowptr, erec, A1 + 256, 512, A1 + 128, 512, -1.f,
                                    nullptr, 512, 0.f, A1 + 384, 512, nullptr, 0, N, 2.0f);

    // --- GEMM1: h1bf = relu(A1 @ W1 + b1) bf16, fused BN1 column stats ---
    gemm_mfma<<<dim3((N + GBM - 1) / GBM, CL1_F / GBN), blk, 0, stream>>>(
        A1, W1t, b1, h1bf, bns1, bnq1, N, CL1_F, 512, 1, 1);

    // --- fold BN1 into W2t + rowvec ---
    fold_w2<<<dim3(512), dim3(256), 0, stream>>>(W2t, bns1, bnq1, gamma1, beta1, rowvec, 1.0f / N);

    // --- GEMM2: Hc = h1bf @ W2t' + rowvec  [M=20000, N=512, K=256] bf16 out ---
    gemm_mfma<<<dim3((N + GBM - 1) / GBM, 512 / GBN), blk, 0, stream>>>(
        h1bf, W2t, rowvec, Hc, nullptr, nullptr, N, 512, 256, 0, 1);

    // --- layer 2 via Clenshaw (F=128 spmms) ---
    spmm_cl<<<gS, blk, 0, stream>>>(rowptr, erec, Hc + 384, 512, Hc + 256, 512, 1.f,
                                    nullptr, 512, 0.f, bb2, 128, nullptr, 0, N, 2.0f);
    spmm_cl<<<gS, blk, 0, stream>>>(rowptr, erec, bb2, 128, Hc + 384, 512, -1.f,
                                    Hc + 128, 512, 1.f, bb1, 128, nullptr, 0, N, 2.0f);
    spmm_cl<<<gS, blk, 0, stream>>>(rowptr, erec, bb1, 128, bb2, 128, -1.f,
                                    Hc + 0, 512, 1.f, pbuf, 128, b2, 1, N, 1.0f);

    // --- BN2 stats ---
    bn_stats_bf<<<dim3((N + BN_ROWS - 1) / BN_ROWS), dim3(CL2_F), 0, stream>>>(pbuf, N, CL2_F, bns2, bnq2);

    // --- final linear with inline BN2 fold ---
    final_linear_bn<<<dim3((N * OUT_F + 255) / 256), blk, 0, stream>>>(
        pbuf, Wlin, blin, bns2, bnq2, gamma2, beta2, out, N, 1.0f / N);
}

// Round 14
// 380.790 us; speedup vs baseline: 1.1859x; 1.0016x over previous
//
#include <hip/hip_runtime.h>
#include <cstdint>
#include <cstddef>

// Problem constants (match reference)
#define NNODES 20000
#define NEDGES 640000
#define IN_F   128
#define CL1_F  256
#define CL2_F  128
#define OUT_F  10
#define BN_EPS 1e-5f

#define NC     256                // edge chunks for cnt/fill (2500 edges each)
#define CE     (NEDGES / NC)
#define HALFN  10000              // node half-range for LDS histograms

// conv workload appended to the hist launch
#define CONVN  (512 * 256 + 4 * 256 * 128 + NNODES * 128)

typedef unsigned short u16;

// ---------------- bf16 helpers ----------------

__device__ __forceinline__ float bf2f(u16 u) {
    union { uint32_t i; float f; } v; v.i = ((uint32_t)u) << 16; return v.f;
}
__device__ __forceinline__ u16 f2bf(float f) {
    union { float f; uint32_t i; } v; v.f = f;
    uint32_t r = v.i + 0x7fffu + ((v.i >> 16) & 1u);   // RNE
    return (u16)(r >> 16);
}
__device__ __forceinline__ void bf2x2(uint32_t u, float& lo, float& hi) {
    union { uint32_t i; float f; } a, b;
    a.i = u << 16; b.i = u & 0xffff0000u;
    lo = a.f; hi = b.f;
}
__device__ __forceinline__ uint32_t f2bf2(float lo, float hi) {
    return (uint32_t)f2bf(lo) | ((uint32_t)f2bf(hi) << 16);
}
__device__ __forceinline__ void unpack8(uint4 v, float* o) {
    bf2x2(v.x, o[0], o[1]); bf2x2(v.y, o[2], o[3]);
    bf2x2(v.z, o[4], o[5]); bf2x2(v.w, o[6], o[7]);
}

// ---------------- fused: CSC hist (blocks 0..NC) + weight/x conversion (rest) ----------------

__launch_bounds__(256)
__global__ void build_hist_conv(const int* __restrict__ ei, const float* __restrict__ ew,
                                u16* __restrict__ cnt_h, u16* __restrict__ degq_h,
                                const float* __restrict__ W1, u16* __restrict__ W1t,
                                const float* __restrict__ W2, u16* __restrict__ W2t,
                                const float* __restrict__ x, u16* __restrict__ A1,
                                int E, int N) {
    __shared__ uint32_t scnt[HALFN / 2];   // 20 KB
    __shared__ uint32_t sdeg[HALFN / 2];   // 20 KB
    int b = blockIdx.x;
    if (b < NC) {
        // ---- per-chunk histogram: dst counts + fixed-point src-degree sums ----
        int e0 = b * CE, e1 = e0 + CE;
        for (int half = 0; half < 2; ++half) {
            int lo = half * HALFN;
            for (int i = threadIdx.x; i < HALFN / 2; i += 256) { scnt[i] = 0; sdeg[i] = 0; }
            __syncthreads();
            for (int e = e0 + threadIdx.x; e < e1; e += 256) {
                int r = ei[e];
                int c = ei[E + e];
                int ci = c - lo;
                if ((unsigned)ci < HALFN) atomicAdd(&scnt[ci >> 1], 1u << ((ci & 1) * 16));
                int ri = r - lo;
                if ((unsigned)ri < HALFN) {
                    float w = (r == c) ? 0.0f : ew[e];
                    uint32_t q = (uint32_t)(w * 1024.0f + 0.5f);
                    atomicAdd(&sdeg[ri >> 1], q << ((ri & 1) * 16));
                }
            }
            __syncthreads();
            for (int i = threadIdx.x; i < HALFN; i += 256) {
                cnt_h[(size_t)b * N + lo + i]  = (u16)((scnt[i >> 1] >> ((i & 1) * 16)) & 0xffffu);
                degq_h[(size_t)b * N + lo + i] = (u16)((sdeg[i >> 1] >> ((i & 1) * 16)) & 0xffffu);
            }
            __syncthreads();
        }
    } else {
        // ---- conversions: W1->W1t, W2->W2t, x->A1 slice0 ----
        int i = (b - NC) * 256 + threadIdx.x;
        const int S1 = 512 * 256;
        const int S2 = 4 * 256 * 128;
        const int SX = NNODES * 128;
        if (i < S1) {
            int k = i / 256, n = i - k * 256;
            W1t[(size_t)n * 512 + k] = f2bf(W1[i]);
        } else if (i < S1 + S2) {
            int j = i - S1;
            int kc = j / (256 * 128);
            int rem = j - kc * 256 * 128;
            int ci = rem / 128, co = rem - ci * 128;
            W2t[(size_t)(kc * 128 + co) * 256 + ci] = f2bf(W2[j]);
        } else if (i < S1 + S2 + SX) {
            int j = i - S1 - S2;
            int n = j >> 7, f = j & 127;
            A1[(size_t)n * 512 + f] = f2bf(x[j]);
        }
    }
}

// fused: per-node totals + dis + per-(chunk,node) fill-base deltas, one cnt_h sweep.
__global__ void reduce_dis_base(const u16* __restrict__ cnt_h, const u16* __restrict__ degq_h,
                                int* __restrict__ tot, float* __restrict__ dis,
                                u16* __restrict__ baseD, int N) {
    int i = blockIdx.x * blockDim.x + threadIdx.x;
    if (i >= N) return;
    int t = 0;
    uint32_t dq = 0;
#pragma unroll 8
    for (int c = 0; c < NC; ++c) {
        baseD[(size_t)c * N + i] = (u16)t;
        t  += cnt_h[(size_t)c * N + i];
        dq += degq_h[(size_t)c * N + i];
    }
    tot[i] = t;
    float d = (float)dq * (1.0f / 1024.0f);
    dis[i] = (d > 0.0f) ? rsqrtf(d) : 0.0f;
}

__global__ void scan_kernel(const int* __restrict__ tot, int* __restrict__ rowptr, int N) {
    __shared__ int sums[256];
    int t = threadIdx.x;
    int per = (N + 255) / 256;
    int s0 = t * per, s1 = min(s0 + per, N);
    int s = 0;
    for (int i = s0; i < s1; ++i) s += tot[i];
    sums[t] = s;
    __syncthreads();
    if (t == 0) {
        int run = 0;
        for (int i = 0; i < 256; ++i) { int v = sums[i]; sums[i] = run; run += v; }
        rowptr[N] = run;
    }
    __syncthreads();
    int run = sums[t];
    for (int i = s0; i < s1; ++i) { rowptr[i] = run; run += tot[i]; }
}

// fill CSC: packed 4-byte records (src u16 | bf16 weight << 16)
__launch_bounds__(256)
__global__ void fill_kernel(const int* __restrict__ ei, const float* __restrict__ ew,
                            const float* __restrict__ dis, const int* __restrict__ rowptr,
                            const u16* __restrict__ baseD,
                            uint32_t* __restrict__ erec, int E, int N) {
    __shared__ uint32_t srank[NNODES / 2];  // 40 KB
    int chunk = blockIdx.x;
    int e0 = chunk * CE, e1 = e0 + CE;
    for (int i = threadIdx.x; i < NNODES / 2; i += 256) srank[i] = 0;
    __syncthreads();
    for (int e = e0 + threadIdx.x; e < e1; e += 256) {
        int r = ei[e];
        int c = ei[E + e];
        float w = (r == c) ? 0.0f : ew[e];
        float wn = -(dis[r] * w * dis[c]);   // * (2/lambda_max) = *1
        int sh = (c & 1) * 16;
        uint32_t old = atomicAdd(&srank[c >> 1], 1u << sh);
        int rank = (old >> sh) & 0xffff;
        int pos = rowptr[c] + (int)baseD[(size_t)chunk * N + c] + rank;
        erec[pos] = (uint32_t)r | ((uint32_t)f2bf(wn) << 16);
    }
}

// ---------------- general spmm (CSC gather, F=128, 16 threads/node, uint4, unroll-8) ----------------
// R14: unroll 4->8 (8 independent row loads in flight per thread). 16-thread/uint4 config
// is proven (R9); R8's regression was the 32-thread/uint2 change, not unroll depth.
__launch_bounds__(256)
__global__ void spmm_cl(const int* __restrict__ rowptr, const uint32_t* __restrict__ erec,
                        const u16* __restrict__ tin, int ldi,
                        const u16* __restrict__ t1, int ld1, float c1,
                        const u16* __restrict__ t2, int ld2, float c2,
                        u16* __restrict__ tout, int ldo,
                        const float* __restrict__ bias, int doReluBias,
                        int N, float s) {
    int gid = blockIdx.x * blockDim.x + threadIdx.x;
    int n = gid >> 4;
    if (n >= N) return;
    int f = (gid & 15) << 3;
    int p = rowptr[n], pe = rowptr[n + 1];
    float acc[8] = {};
    for (; p + 7 < pe; p += 8) {
        uint32_t rr[8];
#pragma unroll
        for (int u = 0; u < 8; ++u) rr[u] = erec[p + u];
        uint4 vv[8];
#pragma unroll
        for (int u = 0; u < 8; ++u)
            vv[u] = *(const uint4*)(tin + (size_t)(rr[u] & 0xffffu) * ldi + f);
#pragma unroll
        for (int u = 0; u < 8; ++u) {
            float w = bf2f((u16)(rr[u] >> 16));
            float fa[8];
            unpack8(vv[u], fa);
#pragma unroll
            for (int q = 0; q < 8; ++q) acc[q] += w * fa[q];
        }
    }
    for (; p < pe; ++p) {
        uint32_t r0 = erec[p];
        uint4 v0 = *(const uint4*)(tin + (size_t)(r0 & 0xffffu) * ldi + f);
        float w0 = bf2f((u16)(r0 >> 16));
        float fa[8];
        unpack8(v0, fa);
#pragma unroll
        for (int q = 0; q < 8; ++q) acc[q] += w0 * fa[q];
    }
#pragma unroll
    for (int q = 0; q < 8; ++q) acc[q] *= s;
    if (t1) {
        uint4 v = *(const uint4*)(t1 + (size_t)n * ld1 + f);
        float fv[8]; unpack8(v, fv);
#pragma unroll
        for (int q = 0; q < 8; ++q) acc[q] += c1 * fv[q];
    }
    if (t2) {
        uint4 v = *(const uint4*)(t2 + (size_t)n * ld2 + f);
        float fv[8]; unpack8(v, fv);
#pragma unroll
        for (int q = 0; q < 8; ++q) acc[q] += c2 * fv[q];
    }
    if (doReluBias) {
#pragma unroll
        for (int q = 0; q < 8; ++q) acc[q] = fmaxf(acc[q] + bias[f + q], 0.0f);
    }
    uint4 o;
    o.x = f2bf2(acc[0], acc[1]);
    o.y = f2bf2(acc[2], acc[3]);
    o.z = f2bf2(acc[4], acc[5]);
    o.w = f2bf2(acc[6], acc[7]);
    *(uint4*)(tout + (size_t)n * ldo + f) = o;
}

// ---------------- bf16 MFMA GEMM, 64x64 tile (+optional fused BN column stats) ----------------

typedef __attribute__((ext_vector_type(8))) short short8;
typedef __attribute__((ext_vector_type(4))) float floatx4;

#define GBM 64
#define GBN 64
#define GBK 64

__launch_bounds__(256)
__global__ void gemm_mfma(const u16* __restrict__ A, const u16* __restrict__ Bt,
                          const float* __restrict__ bias, void* __restrict__ Cout,
                          float* __restrict__ ssum, float* __restrict__ ssq,
                          int M, int N, int K, int doRelu, int outBf) {
    __shared__ __align__(16) u16 As[GBM][GBK + 8];   // stride 144 B
    __shared__ __align__(16) u16 Bs[GBN][GBK + 8];
    __shared__ float colsum[GBN], colsq[GBN];

    int tid = threadIdx.x;
    int lane = tid & 63;
    int wave = tid >> 6;
    int wm = (wave & 1) * 32;
    int wn = (wave >> 1) * 32;
    int rowBase = blockIdx.x * GBM;
    int colBase = blockIdx.y * GBN;

    floatx4 acc[2][2];
#pragma unroll
    for (int i = 0; i < 2; ++i)
#pragma unroll
        for (int j = 0; j < 2; ++j) {
            acc[i][j][0] = 0.f; acc[i][j][1] = 0.f; acc[i][j][2] = 0.f; acc[i][j][3] = 0.f;
        }

    int sr = tid >> 3;             // 0..31
    int sc = (tid & 7) * 8;        // 0..56

    for (int k0 = 0; k0 < K; k0 += GBK) {
#pragma unroll
        for (int h = 0; h < 2; ++h) {
            int r = sr + h * 32;
            int gm = rowBase + r;
            uint4 v = make_uint4(0, 0, 0, 0);
            if (gm < M) v = *(const uint4*)(A + (size_t)gm * K + k0 + sc);
            *(uint4*)&As[r][sc] = v;
            int gn = colBase + r;                    // N multiple of 64 -> no guard
            uint4 w = *(const uint4*)(Bt + (size_t)gn * K + k0 + sc);
            *(uint4*)&Bs[r][sc] = w;
        }
        __syncthreads();

        int mrow = lane & 15;
        int kq = (lane >> 4) * 8;
#pragma unroll
        for (int kk = 0; kk < GBK; kk += 32) {
            short8 af[2], bfr[2];
#pragma unroll
            for (int i = 0; i < 2; ++i) af[i] = *(const short8*)&As[wm + i * 16 + mrow][kk + kq];
#pragma unroll
            for (int j = 0; j < 2; ++j) bfr[j] = *(const short8*)&Bs[wn + j * 16 + mrow][kk + kq];
#pragma unroll
            for (int i = 0; i < 2; ++i)
#pragma unroll
                for (int j = 0; j < 2; ++j)
                    acc[i][j] = __builtin_amdgcn_mfma_f32_16x16x32_bf16(af[i], bfr[j], acc[i][j], 0, 0, 0);
        }
        __syncthreads();
    }

    if (ssum) {
        if (tid < GBN) { colsum[tid] = 0.f; colsq[tid] = 0.f; }
        __syncthreads();
    }

    int cn0 = colBase + wn + (lane & 15);
    int rq = (lane >> 4) * 4;
    float* Cf = (float*)Cout;
    u16*   Cb = (u16*)Cout;
#pragma unroll
    for (int j = 0; j < 2; ++j) {
        float ps = 0.f, pq = 0.f;
        int n = cn0 + j * 16;
#pragma unroll
        for (int i = 0; i < 2; ++i) {
#pragma unroll
            for (int r = 0; r < 4; ++r) {
                int m = rowBase + wm + i * 16 + rq + r;
                if (m >= M) continue;
                float v = acc[i][j][r];
                if (bias) v += bias[n];
                if (doRelu) v = fmaxf(v, 0.0f);
                if (outBf) {
                    u16 bb = f2bf(v);
                    Cb[(size_t)m * N + n] = bb;
                    if (ssum) { float vb = bf2f(bb); ps += vb; pq += vb * vb; }
                } else {
                    Cf[(size_t)m * N + n] = v;
                }
            }
        }
        if (ssum) {
            int lc = wn + j * 16 + (lane & 15);
            atomicAdd(&colsum[lc], ps);
            atomicAdd(&colsq[lc], pq);
        }
    }
    if (ssum) {
        __syncthreads();
        if (tid < GBN) {
            atomicAdd(&ssum[colBase + tid], colsum[tid]);
            atomicAdd(&ssq[colBase + tid], colsq[tid]);
        }
    }
}

// ---------------- batchnorm stats (BN2 only; BN1 fused into GEMM1) ----------------

#define BN_ROWS 64
__global__ void bn_stats_bf(const u16* __restrict__ h, int N, int C,
                            float* __restrict__ sums, float* __restrict__ sumsq) {
    int c = threadIdx.x;
    int r0 = blockIdx.x * BN_ROWS;
    int r1 = min(r0 + BN_ROWS, N);
    float s = 0.f, q = 0.f;
    for (int r = r0; r < r1; ++r) {
        float v = bf2f(h[(size_t)r * C + c]);
        s += v;
        q += v * v;
    }
    atomicAdd(&sums[c], s);
    atomicAdd(&sumsq[c], q);
}

// fold BN1 into W2t (in place); bn_final computed inline per block.
__launch_bounds__(256)
__global__ void fold_w2(u16* __restrict__ W2t, const float* __restrict__ sums,
                        const float* __restrict__ sumsq, const float* __restrict__ gamma,
                        const float* __restrict__ beta, float* __restrict__ rowvec, float invN) {
    __shared__ float red[4];
    int n = blockIdx.x;
    int k = threadIdx.x;
    float m = sums[k] * invN;
    float var = sumsq[k] * invN - m * m;
    float sc = gamma[k] / sqrtf(var + BN_EPS);
    float sh = beta[k] - m * sc;
    float wf = bf2f(W2t[(size_t)n * 256 + k]);
    W2t[(size_t)n * 256 + k] = f2bf(wf * sc);
    float part = sh * wf;
#pragma unroll
    for (int off = 32; off > 0; off >>= 1) part += __shfl_down(part, off);
    if ((k & 63) == 0) red[k >> 6] = part;
    __syncthreads();
    if (k == 0) rowvec[n] = red[0] + red[1] + red[2] + red[3];
}

// ---------------- final linear with inline BN2 fold (bf16 input) ----------------

__global__ void final_linear_bn(const u16* __restrict__ g, const float* __restrict__ Wlin,
                                const float* __restrict__ blin, const float* __restrict__ sums,
                                const float* __restrict__ sumsq, const float* __restrict__ gamma,
                                const float* __restrict__ beta, float* __restrict__ out,
                                int N, float invN) {
    __shared__ float Ws[OUT_F * CL2_F];
    __shared__ float bs[OUT_F];
    __shared__ float scs[CL2_F], shs[CL2_F];
    for (int i = threadIdx.x; i < OUT_F * CL2_F; i += 256) Ws[i] = Wlin[i];
    if (threadIdx.x < OUT_F) bs[threadIdx.x] = blin[threadIdx.x];
    if (threadIdx.x < CL2_F) {
        int c = threadIdx.x;
        float m = sums[c] * invN;
        float var = sumsq[c] * invN - m * m;
        float sc = gamma[c] / sqrtf(var + BN_EPS);
        scs[c] = sc;
        shs[c] = beta[c] - m * sc;
    }
    __syncthreads();
    int idx = blockIdx.x * 256 + threadIdx.x;
    if (idx >= N * OUT_F) return;
    int n = idx / OUT_F, o = idx - n * OUT_F;
    const u16* gr = g + (size_t)n * CL2_F;
    const float* wr = Ws + o * CL2_F;
    float acc = 0.f;
#pragma unroll 8
    for (int f = 0; f < CL2_F; ++f) acc += (bf2f(gr[f]) * scs[f] + shs[f]) * wr[f];
    out[idx] = acc + bs[o];
}

// ---------------- host launch ----------------

extern "C" void kernel_launch(void* const* d_in, const int* in_sizes, int n_in,
                              void* d_out, int out_size, void* d_ws, size_t ws_size,
                              hipStream_t stream) {
    const float* x      = (const float*)d_in[0];
    const int*   ei     = (const int*)d_in[1];
    const float* ew     = (const float*)d_in[2];
    const float* W1     = (const float*)d_in[3];
    const float* b1     = (const float*)d_in[4];
    const float* W2     = (const float*)d_in[5];
    const float* b2     = (const float*)d_in[6];
    const float* gamma1 = (const float*)d_in[7];
    const float* beta1  = (const float*)d_in[8];
    const float* gamma2 = (const float*)d_in[9];
    const float* beta2  = (const float*)d_in[10];
    const float* Wlin   = (const float*)d_in[11];
    const float* blin   = (const float*)d_in[12];
    float* out = (float*)d_out;

    const int N = NNODES, E = NEDGES;

    // workspace (~80.2 MB). baseD is NC*N u16 = 10.24 MB — full extent, no overlap.
    char* base = (char*)d_ws;
    u16*     cnt_h  = (u16*)    (base + 0);           // NC*N u16 = 10.24 MB
    u16*     degq_h = (u16*)    (base + 10240000);    // NC*N u16 = 10.24 MB
    u16*     baseD  = (u16*)    (base + 20480000);    // NC*N u16 = 10.24 MB (ends 30,720,000)
    u16*     A1     = (u16*)    (base + 30720000);    // N*512 bf16 = 20.48 MB
    u16*     Hc     = A1;                             // aliased (A1 dead after GEMM1)
    u16*     h1bf   = (u16*)    (base + 51200000);    // N*256 bf16 = 10.24 MB
    u16*     pbuf   = (u16*)    (base + 61440000);    // N*128 bf16 = 5.12 MB
    u16*     bb2    = (u16*)    (base + 66560000);    // N*128 bf16
    u16*     bb1    = (u16*)    (base + 71680000);    // N*128 bf16
    uint32_t* erec  = (uint32_t*)(base + 76800000);   // E*4 = 2.56 MB
    u16*     W1t    = (u16*)    (base + 79360000);    // 256*512 bf16 = 262144
    u16*     W2t    = (u16*)    (base + 79622144);    // 512*256 bf16 = 262144
    float*   rowvec = (float*)  (base + 79884288);    // 512 f32
    int*     rowptr = (int*)    (base + 79886336);    // N+1
    int*     tot    = (int*)    (base + 79966352);    // N
    float*   dis    = (float*)  (base + 80046352);    // N
    float*   bns1   = (float*)  (base + 80126352);    // 256 (BN1 sums)
    float*   bnq1    = bns1 + 256;                    // 256 (BN1 sumsq)
    float*   bns2    = bnq1 + 256;                    // 256 (BN2 sums; 128 used)
    float*   bnq2    = bns2 + 256;                    // 256 (BN2 sumsq)

    dim3 blk(256);

    // --- zero all BN stat buffers once (GEMM1 accumulates into bns1/bnq1) ---
    hipMemsetAsync(bns1, 0, 4 * 256 * sizeof(float), stream);

    // --- fused: CSC histograms + all dtype conversions in one launch ---
    build_hist_conv<<<dim3(NC + (CONVN + 255) / 256), blk, 0, stream>>>(
        ei, ew, cnt_h, degq_h, W1, W1t, W2, W2t, x, A1, E, N);
    // fused: totals + dis + baseD deltas in one cnt_h/degq_h sweep
    reduce_dis_base<<<dim3((N + 255) / 256), blk, 0, stream>>>(cnt_h, degq_h, tot, dis, baseD, N);
    scan_kernel<<<dim3(1), blk, 0, stream>>>(tot, rowptr, N);
    fill_kernel<<<dim3(NC), blk, 0, stream>>>(ei, ew, dis, rowptr, baseD, erec, E, N);

    dim3 gS(((N << 4) + 255) / 256);   // spmm grid: 16 threads/node

    // --- layer 1: A1 = [x|T1|T2|T3] bf16, ld 512 ---
    spmm_cl<<<gS, blk, 0, stream>>>(rowptr, erec, A1 + 0,   512, nullptr,  512, 0.f,
                                    nullptr, 512, 0.f, A1 + 128, 512, nullptr, 0, N, 1.0f);
    spmm_cl<<<gS, blk, 0, stream>>>(rowptr, erec, A1 + 128, 512, A1 + 0,   512, -1.f,
                                    nullptr, 512, 0.f, A1 + 256, 512, nullptr, 0, N, 2.0f);
    spmm_cl<<<gS, blk, 0, stream>>>(rowptr, erec, A1 + 256, 512, A1 + 128, 512, -1.f,
                                    nullptr, 512, 0.f, A1 + 384, 512, nullptr, 0, N, 2.0f);

    // --- GEMM1: h1bf = relu(A1 @ W1 + b1) bf16, fused BN1 column stats ---
    gemm_mfma<<<dim3((N + GBM - 1) / GBM, CL1_F / GBN), blk, 0, stream>>>(
        A1, W1t, b1, h1bf, bns1, bnq1, N, CL1_F, 512, 1, 1);

    // --- fold BN1 into W2t + rowvec ---
    fold_w2<<<dim3(512), dim3(256), 0, stream>>>(W2t, bns1, bnq1, gamma1, beta1, rowvec, 1.0f / N);

    // --- GEMM2: Hc = h1bf @ W2t' + rowvec  [M=20000, N=512, K=256] bf16 out ---
    gemm_mfma<<<dim3((N + GBM - 1) / GBM, 512 / GBN), blk, 0, stream>>>(
        h1bf, W2t, rowvec, Hc, nullptr, nullptr, N, 512, 256, 0, 1);

    // --- layer 2 via Clenshaw (F=128 spmms) ---
    spmm_cl<<<gS, blk, 0, stream>>>(rowptr, erec, Hc + 384, 512, Hc + 256, 512, 1.f,
                                    nullptr, 512, 0.f, bb2, 128, nullptr, 0, N, 2.0f);
    spmm_cl<<<gS, blk, 0, stream>>>(rowptr, erec, bb2, 128, Hc + 384, 512, -1.f,
                                    Hc + 128, 512, 1.f, bb1, 128, nullptr, 0, N, 2.0f);
    spmm_cl<<<gS, blk, 0, stream>>>(rowptr, erec, bb1, 128, bb2, 128, -1.f,
                                    Hc + 0, 512, 1.f, pbuf, 128, b2, 1, N, 1.0f);

    // --- BN2 stats ---
    bn_stats_bf<<<dim3((N + BN_ROWS - 1) / BN_ROWS), dim3(CL2_F), 0, stream>>>(pbuf, N, CL2_F, bns2, bnq2);

    // --- final linear with inline BN2 fold ---
    final_linear_bn<<<dim3((N * OUT_F + 255) / 256), blk, 0, stream>>>(
        pbuf, Wlin, blin, bns2, bnq2, gamma2, beta2, out, N, 1.0f / N);
}